// Round 5
// baseline (1985.288 us; speedup 1.0000x reference)
//
#include <hip/hip_runtime.h>
#include <hip/hip_bf16.h>

#define DN 100000     // N entities
#define DD 128        // D
#define DR 12         // R relations
#define DNB 8         // bases
#define DE 1000000    // edges
#define DP 400000     // hyperedge incidences
#define DHE 20000     // hyperedges
#define DHE2 40000    // both sides combined
#define DB 64         // batch
#define DLR 64
#define DLC 32
#define DNH 8
#define DHD 16
#define NRBINS (DR * DN)   // 1.2M
#define NALLBINS (NRBINS + DHE2)
#define SCAN_CHUNK 1024
#define MCAP 65536
#define RNECAP 1024   // max edges per 64-dst block (expected ~640; Poisson tail >> cap prob ~0)

typedef unsigned short ushortT;
typedef unsigned int uintT;
typedef __attribute__((ext_vector_type(8))) short s8v;
typedef __attribute__((ext_vector_type(4))) float f4v;

#define APAD 136   // bf16 LDS row stride (272B)
#define AFS 130    // f32 accumulation stride inside U

__device__ __forceinline__ ushortT rneb(float v) {
    uintT b = __float_as_uint(v);
    return (ushortT)((b + 0x7FFFu + ((b >> 16) & 1u)) >> 16);
}
__device__ __forceinline__ float b2f(ushortT h) {
    return __uint_as_float(((uintT)h) << 16);
}

__device__ __forceinline__ void split_store8(ushortT* hbase, ushortT* lbase, const float* v)
{
    ushortT h[8], l[8];
    #pragma unroll
    for (int j = 0; j < 8; ++j) {
        h[j] = rneb(v[j]);
        l[j] = rneb(v[j] - b2f(h[j]));
    }
    uint4 hv = make_uint4((uintT)h[0] | ((uintT)h[1] << 16), (uintT)h[2] | ((uintT)h[3] << 16),
                          (uintT)h[4] | ((uintT)h[5] << 16), (uintT)h[6] | ((uintT)h[7] << 16));
    uint4 lv = make_uint4((uintT)l[0] | ((uintT)l[1] << 16), (uintT)l[2] | ((uintT)l[3] << 16),
                          (uintT)l[4] | ((uintT)l[5] << 16), (uintT)l[6] | ((uintT)l[7] << 16));
    *(uint4*)hbase = hv;
    *(uint4*)lbase = lv;
}

// ---------------------------------------------------------------- weight pre-split (blocked fragment layout)
// WB[kc][n][k] ushort, h plane then l plane at +16384.
// 0 root(t0) 1 sess_theta(t0) 2 know_theta(t0) 3 wq(t1) 4 wk(t1) 5 wv(t1)
// 6 out_proj(t1) 7 attn_his_a(t0) 8 attn_a(t0)
__global__ __launch_bounds__(256) void k_presplit_all(
    const float* __restrict__ root, const float* __restrict__ st,
    const float* __restrict__ kt, const float* __restrict__ ipw,
    const float* __restrict__ opw, const float* __restrict__ aha,
    const float* __restrict__ aa, ushortT* __restrict__ outA)
{
    int gid = blockIdx.x * 256 + threadIdx.x;   // 9*16384 exact
    int mat = gid >> 14, e = gid & 16383;
    const float* srcs[9] = {root, st, kt, ipw, ipw + 16384, ipw + 32768, opw, aha, aa};
    const float* W = srcs[mat];
    bool t1 = (mat >= 3 && mat <= 6);
    int k = e & 31, n = (e >> 5) & 127, kc = e >> 12;
    float f = t1 ? W[(size_t)n * 128 + kc * 32 + k] : W[(size_t)(kc * 32 + k) * 128 + n];
    ushortT h = rneb(f);
    outA[(size_t)mat * 32768 + e] = h;
    outA[(size_t)mat * 32768 + 16384 + e] = rneb(f - b2f(h));
}

// w[r] = comp[r]·bases, split directly into blocked layout (64KB per r: h 32KB, l 32KB)
__global__ void k_wcomp_split(const float* __restrict__ comp, const float* __restrict__ bases,
                              ushortT* __restrict__ warena)
{
    int i = blockIdx.x * blockDim.x + threadIdx.x;
    if (i >= DR * DD * DD) return;
    int r = i / (DD * DD), io = i % (DD * DD);
    float s = 0.f;
    #pragma unroll
    for (int b = 0; b < DNB; ++b) s += comp[r * DNB + b] * bases[(size_t)b * DD * DD + io];
    int irow = io >> 7, o = io & 127;          // irow = k-dim
    int kc = irow >> 5, k = irow & 31;
    size_t dst = (size_t)r * 32768 + (size_t)kc * 4096 + o * 32 + k;
    ushortT h = rneb(s);
    warena[dst] = h;
    warena[dst + 16384] = rneb(s - b2f(h));
}

// ---------------------------------------------------------------- MFMA GEMM, B copy-staged per kc from pre-split global
__global__ __launch_bounds__(256) void k_gemm_ds(
    const float* __restrict__ A, const ushortT* __restrict__ Wb,
    const float* __restrict__ bias, const float* __restrict__ rs,
    const int* __restrict__ gidx, float* __restrict__ gout,
    float* __restrict__ C, int M)
{
    __shared__ __align__(16) ushortT Ah[64 * APAD], Al[64 * APAD];
    __shared__ __align__(16) ushortT Bs[8192];
    int tid = threadIdx.x;
    int row0 = blockIdx.x * 64;
    {
        int row = tid >> 2, c0 = (tid & 3) * 32;
        int gr = row0 + row;
        int arow = gr;
        if (gidx && gr < M) arow = gidx[gr];
        const float* ar = A + (size_t)arow * 128 + c0;
        float sc = 1.0f;
        if (rs && gr < M) { float d = rs[gr]; sc = (d > 0.f) ? 1.0f / d : 0.f; }
        #pragma unroll
        for (int g = 0; g < 4; ++g) {
            float v[8] = {};
            if (gr < M) {
                float4 u0 = *(const float4*)(ar + g * 8);
                float4 u1 = *(const float4*)(ar + g * 8 + 4);
                v[0]=u0.x*sc; v[1]=u0.y*sc; v[2]=u0.z*sc; v[3]=u0.w*sc;
                v[4]=u1.x*sc; v[5]=u1.y*sc; v[6]=u1.z*sc; v[7]=u1.w*sc;
                if (gout) {
                    *(float4*)(gout + (size_t)gr * 128 + c0 + g * 8)     = u0;
                    *(float4*)(gout + (size_t)gr * 128 + c0 + g * 8 + 4) = u1;
                }
            }
            split_store8(&Ah[row * APAD + c0 + g * 8], &Al[row * APAD + c0 + g * 8], v);
        }
    }
    f4v acc[8] = {};
    int w = tid >> 6, lane = tid & 63, m = lane & 15, quad = lane >> 4;
    for (int kc = 0; kc < 4; ++kc) {
        __syncthreads();
        {
            const ushortT* gh = Wb + kc * 4096;
            const ushortT* gl = Wb + 16384 + kc * 4096;
            *(s8v*)&Bs[tid * 8]        = *(const s8v*)&gh[tid * 8];
            *(s8v*)&Bs[2048 + tid * 8] = *(const s8v*)&gh[2048 + tid * 8];
            *(s8v*)&Bs[4096 + tid * 8] = *(const s8v*)&gl[tid * 8];
            *(s8v*)&Bs[6144 + tid * 8] = *(const s8v*)&gl[2048 + tid * 8];
        }
        __syncthreads();
        s8v ah = *(const s8v*)&Ah[(w * 16 + m) * APAD + kc * 32 + quad * 8];
        s8v al = *(const s8v*)&Al[(w * 16 + m) * APAD + kc * 32 + quad * 8];
        #pragma unroll
        for (int nt = 0; nt < 8; ++nt) {
            int boff = (nt * 16 + m) * 32 + quad * 8;
            s8v bh = *(const s8v*)&Bs[boff];
            s8v bl = *(const s8v*)&Bs[4096 + boff];
            acc[nt] = __builtin_amdgcn_mfma_f32_16x16x32_bf16(ah, bh, acc[nt], 0, 0, 0);
            acc[nt] = __builtin_amdgcn_mfma_f32_16x16x32_bf16(al, bh, acc[nt], 0, 0, 0);
            acc[nt] = __builtin_amdgcn_mfma_f32_16x16x32_bf16(ah, bl, acc[nt], 0, 0, 0);
        }
    }
    float bv[8];
    #pragma unroll
    for (int nt = 0; nt < 8; ++nt) bv[nt] = bias ? bias[nt * 16 + m] : 0.f;
    #pragma unroll
    for (int rr = 0; rr < 4; ++rr) {
        int gr = row0 + w * 16 + quad * 4 + rr;
        if (gr < M) {
            #pragma unroll
            for (int nt = 0; nt < 8; ++nt)
                C[(size_t)gr * 128 + nt * 16 + m] = acc[nt][rr] + bv[nt];
        }
    }
}

// ---------------------------------------------------------------- fused e[row] = tanh(A@W)[row,:] . bvec
__global__ __launch_bounds__(256) void k_tanh_dot_ds(
    const float* __restrict__ A, const ushortT* __restrict__ Wb,
    const float* __restrict__ bvec, float* __restrict__ e, int M)
{
    __shared__ __align__(16) ushortT Ah[64 * APAD], Al[64 * APAD];
    __shared__ __align__(16) ushortT Bs[8192];
    int tid = threadIdx.x;
    int row0 = blockIdx.x * 64;
    {
        int row = tid >> 2, c0 = (tid & 3) * 32;
        int gr = row0 + row;
        const float* ar = A + (size_t)gr * 128 + c0;
        #pragma unroll
        for (int g = 0; g < 4; ++g) {
            float v[8] = {};
            if (gr < M) {
                float4 u0 = *(const float4*)(ar + g * 8);
                float4 u1 = *(const float4*)(ar + g * 8 + 4);
                v[0]=u0.x; v[1]=u0.y; v[2]=u0.z; v[3]=u0.w;
                v[4]=u1.x; v[5]=u1.y; v[6]=u1.z; v[7]=u1.w;
            }
            split_store8(&Ah[row * APAD + c0 + g * 8], &Al[row * APAD + c0 + g * 8], v);
        }
    }
    f4v acc[8] = {};
    int w = tid >> 6, lane = tid & 63, m = lane & 15, quad = lane >> 4;
    for (int kc = 0; kc < 4; ++kc) {
        __syncthreads();
        {
            const ushortT* gh = Wb + kc * 4096;
            const ushortT* gl = Wb + 16384 + kc * 4096;
            *(s8v*)&Bs[tid * 8]        = *(const s8v*)&gh[tid * 8];
            *(s8v*)&Bs[2048 + tid * 8] = *(const s8v*)&gh[2048 + tid * 8];
            *(s8v*)&Bs[4096 + tid * 8] = *(const s8v*)&gl[tid * 8];
            *(s8v*)&Bs[6144 + tid * 8] = *(const s8v*)&gl[2048 + tid * 8];
        }
        __syncthreads();
        s8v ah = *(const s8v*)&Ah[(w * 16 + m) * APAD + kc * 32 + quad * 8];
        s8v al = *(const s8v*)&Al[(w * 16 + m) * APAD + kc * 32 + quad * 8];
        #pragma unroll
        for (int nt = 0; nt < 8; ++nt) {
            int boff = (nt * 16 + m) * 32 + quad * 8;
            s8v bh = *(const s8v*)&Bs[boff];
            s8v bl = *(const s8v*)&Bs[4096 + boff];
            acc[nt] = __builtin_amdgcn_mfma_f32_16x16x32_bf16(ah, bh, acc[nt], 0, 0, 0);
            acc[nt] = __builtin_amdgcn_mfma_f32_16x16x32_bf16(al, bh, acc[nt], 0, 0, 0);
            acc[nt] = __builtin_amdgcn_mfma_f32_16x16x32_bf16(ah, bl, acc[nt], 0, 0, 0);
        }
    }
    float bv[8];
    #pragma unroll
    for (int nt = 0; nt < 8; ++nt) bv[nt] = bvec[nt * 16 + m];
    #pragma unroll
    for (int rr = 0; rr < 4; ++rr) {
        float p = 0.f;
        #pragma unroll
        for (int nt = 0; nt < 8; ++nt) p += tanhf(acc[nt][rr]) * bv[nt];
        #pragma unroll
        for (int o = 1; o < 16; o <<= 1) p += __shfl_xor(p, o);
        int gr = row0 + w * 16 + quad * 4 + rr;
        if (m == 0 && gr < M) e[gr] = p;
    }
}

// ---------------------------------------------------------------- softmax(e) weighted sum of h rows (+ optional user split)
template <int L>
__global__ __launch_bounds__(128) void k_pool_apply(const float* __restrict__ h,
                                                    const float* __restrict__ e,
                                                    float* __restrict__ out,
                                                    ushortT* __restrict__ us)
{
    __shared__ float es[L];
    int b = blockIdx.x, tid = threadIdx.x;
    if (tid < L) es[tid] = e[b * L + tid];
    __syncthreads();
    float mx = -1e30f;
    #pragma unroll
    for (int l = 0; l < L; ++l) mx = fmaxf(mx, es[l]);
    float wgt[L];
    float sum = 0.f;
    #pragma unroll
    for (int l = 0; l < L; ++l) { wgt[l] = __expf(es[l] - mx); sum += wgt[l]; }
    float inv = 1.0f / sum;
    float o = 0.f;
    #pragma unroll
    for (int l = 0; l < L; ++l) o += wgt[l] * h[((size_t)b * L + l) * 128 + tid];
    float val = o * inv;
    out[(size_t)b * 128 + tid] = val;
    if (us) {
        ushortT hh = rneb(val);
        ushortT ll = rneb(val - b2f(hh));
        int e_ = ((tid >> 5) * 2048) + b * 32 + (tid & 31);
        us[e_] = hh;
        us[8192 + e_] = ll;
    }
}

__global__ void k_build_ucat(const float* __restrict__ ctx, const float* __restrict__ his,
                             float* ucat)
{
    int i = blockIdx.x * blockDim.x + threadIdx.x;
    if (i >= DB * 33 * 128) return;
    int d = i & 127, l = (i >> 7) % 33, b = i / (33 * 128);
    ucat[i] = (l < 32) ? ctx[((size_t)b * 32 + l) * 128 + d] : his[(size_t)b * 128 + d];
}

// ---------------------------------------------------------------- fused root + RGCN: one block owns 64 dsts, 13 phases,
// non-atomic single kg write. Edges sorted by key = dst*DR + r -> block edge range is contiguous.
__global__ __launch_bounds__(256) void k_rgcn_fused(
    const float* __restrict__ x, const ushortT* __restrict__ rootsplit,
    const ushortT* __restrict__ warena, const float* __restrict__ bias,
    const int* __restrict__ soff, const int* __restrict__ hist,
    const int* __restrict__ ssrc, float* __restrict__ kg)
{
    __shared__ __align__(16) float U[64 * APAD / 2 * 2];  // 64*136 floats: Af (f32, stride AFS) / Ah+Al (ushort, stride APAD) overlay
    __shared__ __align__(16) ushortT Bs[8192];
    __shared__ ushortT rowr[RNECAP];                      // per-edge tag: (localRow<<4) | r
    ushortT* Ah = (ushortT*)U;
    ushortT* Al = (ushortT*)U + 64 * APAD;
    int tid = threadIdx.x;
    int dst0 = blockIdx.x * 64;
    int nrow = min(64, DN - dst0);
    int kfirst = dst0 * DR;
    int klast  = (dst0 + nrow) * DR - 1;
    int st0 = soff[kfirst] - hist[kfirst];   // soff is in-place inclusive end after bucketing
    int ne  = soff[klast] - st0;
    bool fb = (ne > RNECAP);
    int w = tid >> 6, lane = tid & 63, m = lane & 15, quad = lane >> 4;
    int row = tid >> 2, c0 = (tid & 3) * 32;
    f4v acc[8] = {};

    if (!fb) {
        for (int kk = tid; kk < nrow * DR; kk += 256) {
            int key = kfirst + kk;
            int len = hist[key];
            int st = soff[key] - len - st0;
            ushortT tag = (ushortT)(((kk / DR) << 4) | (kk % DR));
            for (int i = 0; i < len; ++i) rowr[st + i] = tag;
        }
    }

    for (int p = 0; p < 13; ++p) {
        __syncthreads();   // all LDS reads of previous phase complete (U is overlaid)
        if (p == 0) {
            // root: A = x[dst] directly (contiguous rows)
            float a[32] = {};
            if (row < nrow) {
                const float* ar = x + (size_t)(dst0 + row) * 128 + c0;
                #pragma unroll
                for (int j = 0; j < 8; ++j) {
                    float4 v = *(const float4*)(ar + j * 4);
                    a[j*4+0]=v.x; a[j*4+1]=v.y; a[j*4+2]=v.z; a[j*4+3]=v.w;
                }
            }
            #pragma unroll
            for (int g = 0; g < 4; ++g)
                split_store8(&Ah[row * APAD + c0 + g * 8], &Al[row * APAD + c0 + g * 8], a + g * 8);
        } else if (!fb) {
            int r = p - 1;
            for (int i = tid; i < 64 * AFS; i += 256) U[i] = 0.f;
            __syncthreads();
            // cooperative gather: one wave iteration = one edge = one full 512B x-row (coalesced);
            // skip is wave-uniform (64 tasks per edge). LDS f32 atomics, 2-way bank alias (free).
            for (int t = tid; t < ne * 64; t += 256) {
                int e = t >> 6;
                ushortT tg = rowr[e];
                if ((tg & 15) != r) continue;
                int rw = tg >> 4, c = t & 63;
                int src = ssrc[st0 + e];
                float2 v = *(const float2*)&x[(size_t)src * 128 + c * 2];
                atomicAdd(&U[rw * AFS + c * 2 + 0], v.x);
                atomicAdd(&U[rw * AFS + c * 2 + 1], v.y);
            }
            __syncthreads();
            int len = (row < nrow) ? hist[(dst0 + row) * DR + r] : 0;
            float inv = (len > 0) ? 1.0f / (float)len : 0.f;
            float a[32];
            #pragma unroll
            for (int j = 0; j < 32; ++j) a[j] = U[row * AFS + c0 + j] * inv;
            __syncthreads();   // all Af reads done before overlay writes
            #pragma unroll
            for (int g = 0; g < 4; ++g)
                split_store8(&Ah[row * APAD + c0 + g * 8], &Al[row * APAD + c0 + g * 8], a + g * 8);
        } else {
            // fallback (ne > cap): serial per-row gather
            int r = p - 1;
            float a[32] = {};
            if (row < nrow) {
                int key = (dst0 + row) * DR + r;
                int len = hist[key];
                int st = soff[key] - len;
                for (int i = 0; i < len; ++i) {
                    const float* xr = x + (size_t)ssrc[st + i] * 128 + c0;
                    #pragma unroll
                    for (int j = 0; j < 8; ++j) {
                        float4 v = *(const float4*)(xr + j * 4);
                        a[j*4+0]+=v.x; a[j*4+1]+=v.y; a[j*4+2]+=v.z; a[j*4+3]+=v.w;
                    }
                }
                float inv = (len > 0) ? 1.0f / (float)len : 0.f;
                #pragma unroll
                for (int j = 0; j < 32; ++j) a[j] *= inv;
            }
            #pragma unroll
            for (int g = 0; g < 4; ++g)
                split_store8(&Ah[row * APAD + c0 + g * 8], &Al[row * APAD + c0 + g * 8], a + g * 8);
        }
        const ushortT* Wb = (p == 0) ? rootsplit : warena + (size_t)(p - 1) * 32768;
        for (int kc = 0; kc < 4; ++kc) {
            __syncthreads();
            const ushortT* gh = Wb + kc * 4096;
            const ushortT* gl = Wb + 16384 + kc * 4096;
            *(s8v*)&Bs[tid * 8]        = *(const s8v*)&gh[tid * 8];
            *(s8v*)&Bs[2048 + tid * 8] = *(const s8v*)&gh[2048 + tid * 8];
            *(s8v*)&Bs[4096 + tid * 8] = *(const s8v*)&gl[tid * 8];
            *(s8v*)&Bs[6144 + tid * 8] = *(const s8v*)&gl[2048 + tid * 8];
            __syncthreads();
            s8v ah = *(const s8v*)&Ah[(w * 16 + m) * APAD + kc * 32 + quad * 8];
            s8v al = *(const s8v*)&Al[(w * 16 + m) * APAD + kc * 32 + quad * 8];
            #pragma unroll
            for (int nt = 0; nt < 8; ++nt) {
                int boff = (nt * 16 + m) * 32 + quad * 8;
                s8v bh = *(const s8v*)&Bs[boff];
                s8v bl = *(const s8v*)&Bs[4096 + boff];
                acc[nt] = __builtin_amdgcn_mfma_f32_16x16x32_bf16(ah, bh, acc[nt], 0, 0, 0);
                acc[nt] = __builtin_amdgcn_mfma_f32_16x16x32_bf16(al, bh, acc[nt], 0, 0, 0);
                acc[nt] = __builtin_amdgcn_mfma_f32_16x16x32_bf16(ah, bl, acc[nt], 0, 0, 0);
            }
        }
    }
    float bv[8];
    #pragma unroll
    for (int nt = 0; nt < 8; ++nt) bv[nt] = bias[nt * 16 + m];
    #pragma unroll
    for (int rr = 0; rr < 4; ++rr) {
        int gr = dst0 + w * 16 + quad * 4 + rr;
        if (gr < DN) {
            #pragma unroll
            for (int nt = 0; nt < 8; ++nt)
                kg[(size_t)gr * 128 + nt * 16 + m] = acc[nt][rr] + bv[nt];
        }
    }
}

// ---------------------------------------------------------------- scoring (MFMA, B copy-staged from pre-split user)
__global__ __launch_bounds__(256) void k_score_ds(
    const float* __restrict__ kg, const ushortT* __restrict__ Ub,
    const float* __restrict__ rb, float* __restrict__ out)
{
    __shared__ __align__(16) ushortT Ah[64 * APAD], Al[64 * APAD];
    __shared__ __align__(16) ushortT Bs[4096];
    int tid = threadIdx.x;
    int n0 = blockIdx.x * 64;
    {
        int row = tid >> 2, c0 = (tid & 3) * 32;
        int gr = n0 + row;
        const float* ar = kg + (size_t)gr * 128 + c0;
        #pragma unroll
        for (int g = 0; g < 4; ++g) {
            float v[8] = {};
            if (gr < DN) {
                float4 u0 = *(const float4*)(ar + g * 8);
                float4 u1 = *(const float4*)(ar + g * 8 + 4);
                v[0]=u0.x; v[1]=u0.y; v[2]=u0.z; v[3]=u0.w;
                v[4]=u1.x; v[5]=u1.y; v[6]=u1.z; v[7]=u1.w;
            }
            split_store8(&Ah[row * APAD + c0 + g * 8], &Al[row * APAD + c0 + g * 8], v);
        }
    }
    f4v acc[4] = {};
    int w = tid >> 6, lane = tid & 63, m = lane & 15, quad = lane >> 4;
    for (int kc = 0; kc < 4; ++kc) {
        __syncthreads();
        {
            const ushortT* gh = Ub + kc * 2048;
            const ushortT* gl = Ub + 8192 + kc * 2048;
            *(s8v*)&Bs[tid * 8]        = *(const s8v*)&gh[tid * 8];
            *(s8v*)&Bs[2048 + tid * 8] = *(const s8v*)&gl[tid * 8];
        }
        __syncthreads();
        s8v ah = *(const s8v*)&Ah[(w * 16 + m) * APAD + kc * 32 + quad * 8];
        s8v al = *(const s8v*)&Al[(w * 16 + m) * APAD + kc * 32 + quad * 8];
        #pragma unroll
        for (int nt = 0; nt < 4; ++nt) {
            int boff = (nt * 16 + m) * 32 + quad * 8;
            s8v bh = *(const s8v*)&Bs[boff];
            s8v bl = *(const s8v*)&Bs[2048 + boff];
            acc[nt] = __builtin_amdgcn_mfma_f32_16x16x32_bf16(ah, bh, acc[nt], 0, 0, 0);
            acc[nt] = __builtin_amdgcn_mfma_f32_16x16x32_bf16(al, bh, acc[nt], 0, 0, 0);
            acc[nt] = __builtin_amdgcn_mfma_f32_16x16x32_bf16(ah, bl, acc[nt], 0, 0, 0);
        }
    }
    int n = n0 + w * 16 + quad * 4;
    if (n < DN) {
        float4 rbv = *(const float4*)&rb[n];
        #pragma unroll
        for (int nt = 0; nt < 4; ++nt) {
            int b = nt * 16 + m;
            float4 o = make_float4(acc[nt][0] + rbv.x, acc[nt][1] + rbv.y,
                                   acc[nt][2] + rbv.z, acc[nt][3] + rbv.w);
            *(float4*)&out[(size_t)b * DN + n] = o;
        }
    }
}

// ---------------------------------------------------------------- scans (single merged array: rgcn bins + hyper bins)
__global__ void k_scan_pass1(const int* __restrict__ in, int n, int* __restrict__ bsum)
{
    __shared__ int red[256];
    int b = blockIdx.x, t = threadIdx.x;
    int i0 = b * SCAN_CHUNK + t * 4;
    int s = 0;
    #pragma unroll
    for (int j = 0; j < 4; ++j) {
        int i = i0 + j;
        if (i < n) s += in[i];
    }
    red[t] = s;
    __syncthreads();
    for (int o = 128; o > 0; o >>= 1) {
        if (t < o) red[t] += red[t + o];
        __syncthreads();
    }
    if (t == 0) bsum[b] = red[0];
}

__global__ __launch_bounds__(256) void k_scan_pass2p(int* bsum, int nb, int* total)
{
    __shared__ int lds[256];
    __shared__ int carry;
    int t = threadIdx.x;
    if (t == 0) carry = 0;
    __syncthreads();
    for (int c0 = 0; c0 < nb; c0 += 256) {
        int i = c0 + t;
        int v = (i < nb) ? bsum[i] : 0;
        lds[t] = v;
        __syncthreads();
        for (int o = 1; o < 256; o <<= 1) {
            int add = (t >= o) ? lds[t - o] : 0;
            __syncthreads();
            lds[t] += add;
            __syncthreads();
        }
        int myc = carry;
        if (i < nb) bsum[i] = lds[t] - v + myc;
        int tot = lds[255];
        __syncthreads();
        if (t == 0) carry = myc + tot;
        __syncthreads();
    }
    if (total && t == 0) *total = carry;
}

__global__ void k_scan_pass3(const int* __restrict__ in, int n, const int* __restrict__ bsum,
                             int* __restrict__ out)
{
    __shared__ int lds[256];
    int b = blockIdx.x, t = threadIdx.x;
    int i0 = b * SCAN_CHUNK + t * 4;
    int v[4]; int s = 0;
    #pragma unroll
    for (int j = 0; j < 4; ++j) {
        int i = i0 + j;
        int x = 0;
        if (i < n) x = in[i];
        v[j] = x; s += x;
    }
    lds[t] = s;
    __syncthreads();
    for (int o = 1; o < 256; o <<= 1) {
        int add = (t >= o) ? lds[t - o] : 0;
        __syncthreads();
        lds[t] += add;
        __syncthreads();
    }
    int run = lds[t] - s + bsum[b];
    #pragma unroll
    for (int j = 0; j < 4; ++j) {
        int i = i0 + j;
        if (i < n) { out[i] = run; run += v[j]; }
    }
}

// ---------------------------------------------------------------- merged histogram (RGCN key = dst*DR + et; hyper at +NRBINS)
__global__ void k_hist_both(const int* __restrict__ dst, const int* __restrict__ et,
                            int* __restrict__ hist,
                            const int* __restrict__ se, const int* __restrict__ ke)
{
    int i = blockIdx.x * blockDim.x + threadIdx.x;
    if (i < DE) {
        atomicAdd(&hist[dst[i] * DR + et[i]], 1);
    } else {
        int j = i - DE;
        if (j < DP) atomicAdd(&hist[NRBINS + se[j]], 1);
        else if (j < 2 * DP) atomicAdd(&hist[NRBINS + DHE + ke[j - DP]], 1);
    }
}

// merged bucket scatter (in-place cursor). Hyper positions are offset by DE (concat prefix) -> pns[pos-DE].
__global__ void k_bucket_both(const int* __restrict__ src, const int* __restrict__ dst,
                              const int* __restrict__ et, int* __restrict__ soff,
                              int* __restrict__ ssrc,
                              const int* __restrict__ sn, const int* __restrict__ se,
                              const int* __restrict__ kn, const int* __restrict__ ke,
                              int* __restrict__ pns)
{
    int i = blockIdx.x * blockDim.x + threadIdx.x;
    if (i < DE) {
        int key = dst[i] * DR + et[i];
        int pos = atomicAdd(&soff[key], 1);
        ssrc[pos] = src[i];
    } else {
        int j = i - DE;
        if (j >= 2 * DP) return;
        int e, node;
        if (j < DP) { e = se[j]; node = sn[j]; }
        else { e = DHE + ke[j - DP]; node = kn[j - DP]; }
        int pos = atomicAdd(&soff[NRBINS + e], 1);
        pns[pos - DE] = node;
    }
}

// one wave per NEEDED hyperedge; st from in-place cursor (minus DE concat offset)
__global__ void k_hyper_agg(const float* __restrict__ xsrc, const int* __restrict__ pns,
                            const int* __restrict__ hoff, const int* __restrict__ hcnt,
                            const int* __restrict__ heneed, float* __restrict__ efeat)
{
    int lane = threadIdx.x & 63;
    int he = (blockIdx.x * blockDim.x + threadIdx.x) >> 6;
    if (he >= DHE2) return;
    if (!heneed[he]) return;
    int len = hcnt[he];
    int st = hoff[he] - len - DE;
    int half = lane >> 5;
    int c16 = (lane & 31) * 4;
    float4 acc = make_float4(0.f, 0.f, 0.f, 0.f);
    int c = 0;
    for (; c + 4 <= len; c += 4) {
        int n0 = pns[st + c + half];
        int n1 = pns[st + c + 2 + half];
        float4 v0 = *(const float4*)&xsrc[(size_t)n0 * 128 + c16];
        float4 v1 = *(const float4*)&xsrc[(size_t)n1 * 128 + c16];
        acc.x += v0.x + v1.x; acc.y += v0.y + v1.y;
        acc.z += v0.z + v1.z; acc.w += v0.w + v1.w;
    }
    for (; c < len; c += 2) {
        int idx = c + half;
        if (idx < len) {
            int n = pns[st + idx];
            float4 v = *(const float4*)&xsrc[(size_t)n * 128 + c16];
            acc.x += v.x; acc.y += v.y; acc.z += v.z; acc.w += v.w;
        }
    }
    acc.x += __shfl_xor(acc.x, 32);
    acc.y += __shfl_xor(acc.y, 32);
    acc.z += __shfl_xor(acc.z, 32);
    acc.w += __shfl_xor(acc.w, 32);
    if (half == 0) {
        float inv = (len > 0) ? 1.0f / (float)len : 0.f;
        float4 o = make_float4(acc.x * inv, acc.y * inv, acc.z * inv, acc.w * inv);
        *(float4*)&efeat[(size_t)he * 128 + c16] = o;
    }
}

__global__ void k_slot_assign2(const int* __restrict__ sidx, const int* __restrict__ kidx,
                               int* slot_s, int* slot_k, int* scnt)
{
    int i = blockIdx.x * blockDim.x + threadIdx.x;
    if (i < DB * DLR) {
        int node = sidx[i];
        if (atomicCAS(&slot_s[node], -1, -2) == -1) slot_s[node] = atomicAdd(&scnt[0], 1);
    } else if (i < 2 * DB * DLR) {
        int node = kidx[i - DB * DLR];
        if (atomicCAS(&slot_k[node], -1, -2) == -1) slot_k[node] = atomicAdd(&scnt[1], 1);
    }
}

// fused sdeg + match + need-flag, block-aggregated compaction
__global__ __launch_bounds__(256) void k_sdeg_match(
    const int* __restrict__ nodes, const int* __restrict__ he, const int* __restrict__ slot,
    float* sdeg, int* mcnt, int* mhe, int* msl, int* heneed, int heBase)
{
    __shared__ int lcnt, lbase;
    if (threadIdx.x == 0) lcnt = 0;
    __syncthreads();
    int i = blockIdx.x * 256 + threadIdx.x;
    int s = -1, lidx = 0, h = 0;
    if (i < DP) {
        s = slot[nodes[i]];
        if (s >= 0) {
            h = heBase + he[i];
            heneed[h] = 1;
            atomicAdd(&sdeg[s], 1.0f);
            lidx = atomicAdd(&lcnt, 1);
        }
    }
    __syncthreads();
    if (threadIdx.x == 0) lbase = (lcnt > 0) ? atomicAdd(mcnt, lcnt) : 0;
    __syncthreads();
    if (s >= 0) {
        int idx = lbase + lidx;
        if (idx < MCAP) { mhe[idx] = h; msl[idx] = s; }
    }
}

// both sides in one launch
__global__ void k_accmatch2(const float* __restrict__ efeat,
                            const int* __restrict__ mhe_s, const int* __restrict__ msl_s,
                            const int* __restrict__ mhe_k, const int* __restrict__ msl_k,
                            const int* __restrict__ mcnt,
                            float* sacc_s, float* sacc_k)
{
    int lane = threadIdx.x & 63;
    int w = (blockIdx.x * blockDim.x + threadIdx.x) >> 6;
    int nw = (gridDim.x * blockDim.x) >> 6;
    int Ms = min(mcnt[0], MCAP), Mk = min(mcnt[1], MCAP);
    for (int i = w; i < Ms + Mk; i += nw) {
        bool sess = i < Ms;
        int he = sess ? mhe_s[i] : mhe_k[i - Ms];
        int sl = sess ? msl_s[i] : msl_k[i - Ms];
        float* sacc = sess ? sacc_s : sacc_k;
        float2 v = *(const float2*)&efeat[(size_t)he * 128 + lane * 2];
        atomicAdd(&sacc[(size_t)sl * 128 + lane * 2],     v.x);
        atomicAdd(&sacc[(size_t)sl * 128 + lane * 2 + 1], v.y);
    }
}

// both sides in one launch
__global__ void k_rel_gather2(const float* __restrict__ so_s, const float* __restrict__ so_k,
                              const int* __restrict__ slot_s, const int* __restrict__ slot_k,
                              const int* __restrict__ ridx_s, const int* __restrict__ ridx_k,
                              float* __restrict__ related)
{
    int gid = blockIdx.x * blockDim.x + threadIdx.x;
    int i = gid >> 5, c = gid & 31;
    if (i >= 2 * DB * DLR) return;
    bool sess = i < DB * DLR;
    int ii = sess ? i : i - DB * DLR;
    int s = sess ? slot_s[ridx_s[ii]] : slot_k[ridx_k[ii]];
    const float* so = sess ? so_s : so_k;
    int b = ii / DLR, l = ii % DLR;
    int colOff = sess ? 0 : 64;
    ((float4*)&related[((size_t)b * 128 + colOff + l) * 128])[c] =
        ((const float4*)&so[(size_t)s * 128])[c];
}

// ---------------------------------------------------------------- MHA: one block per (b,h)
__global__ __launch_bounds__(256) void k_mha(const float* __restrict__ qb,
                                             const float* __restrict__ kb,
                                             const float* __restrict__ vb,
                                             float* __restrict__ ob)
{
    int b = blockIdx.x >> 3, h = blockIdx.x & 7;
    __shared__ float Ks[128][16], Vs[128][16], Qs[32][16];
    int tid = threadIdx.x;
    for (int i = tid; i < 128 * 16; i += 256) {
        int j = i >> 4, d = i & 15;
        Ks[j][d] = kb[((size_t)b * 128 + j) * 128 + h * 16 + d];
        Vs[j][d] = vb[((size_t)b * 128 + j) * 128 + h * 16 + d];
    }
    for (int i = tid; i < 32 * 16; i += 256) {
        int q = i >> 4, d = i & 15;
        Qs[q][d] = qb[((size_t)b * 32 + q) * 128 + h * 16 + d] * 0.25f;
    }
    __syncthreads();
    int q = tid >> 3;
    int jg = tid & 7;
    float lg[16];
    float m = -1e30f;
    #pragma unroll
    for (int jj = 0; jj < 16; ++jj) {
        int j = jg * 16 + jj;
        float s = 0.f;
        #pragma unroll
        for (int d = 0; d < 16; ++d) s += Qs[q][d] * Ks[j][d];
        lg[jj] = s;
        m = fmaxf(m, s);
    }
    #pragma unroll
    for (int o = 1; o < 8; o <<= 1) m = fmaxf(m, __shfl_xor(m, o));
    float sum = 0.f;
    float acc[16] = {};
    #pragma unroll
    for (int jj = 0; jj < 16; ++jj) {
        float p = __expf(lg[jj] - m);
        sum += p;
        int j = jg * 16 + jj;
        #pragma unroll
        for (int d = 0; d < 16; ++d) acc[d] += p * Vs[j][d];
    }
    #pragma unroll
    for (int o = 1; o < 8; o <<= 1) {
        sum += __shfl_xor(sum, o);
        #pragma unroll
        for (int d = 0; d < 16; ++d) acc[d] += __shfl_xor(acc[d], o);
    }
    if (jg == 0) {
        float inv = 1.0f / sum;
        #pragma unroll
        for (int d = 0; d < 16; ++d)
            ob[((size_t)b * 32 + q) * 128 + h * 16 + d] = acc[d] * inv;
    }
}

// ---------------------------------------------------------------- launch
extern "C" void kernel_launch(void* const* d_in, const int* in_sizes, int n_in,
                              void* d_out, int out_size, void* d_ws, size_t ws_size,
                              hipStream_t stream)
{
    const float* emb        = (const float*)d_in[0];
    const float* bases      = (const float*)d_in[1];
    const float* comp       = (const float*)d_in[2];
    const float* root       = (const float*)d_in[3];
    const float* rgcn_bias  = (const float*)d_in[4];
    const float* sess_theta = (const float*)d_in[5];
    const float* sess_bias  = (const float*)d_in[6];
    const float* know_theta = (const float*)d_in[7];
    const float* know_bias  = (const float*)d_in[8];
    const float* in_proj_w  = (const float*)d_in[9];
    const float* in_proj_b  = (const float*)d_in[10];
    const float* out_proj_w = (const float*)d_in[11];
    const float* out_proj_b = (const float*)d_in[12];
    const float* attn_his_a = (const float*)d_in[13];
    const float* attn_his_b = (const float*)d_in[14];
    const float* attn_a     = (const float*)d_in[15];
    const float* attn_b     = (const float*)d_in[16];
    const float* rec_bias   = (const float*)d_in[17];
    const int* edge_src     = (const int*)d_in[18];
    const int* edge_dst     = (const int*)d_in[19];
    const int* edge_type    = (const int*)d_in[20];
    const int* sess_nodes   = (const int*)d_in[21];
    const int* sess_edges   = (const int*)d_in[22];
    const int* know_nodes   = (const int*)d_in[23];
    const int* know_edges   = (const int*)d_in[24];
    const int* sess_rel_idx = (const int*)d_in[25];
    const int* know_rel_idx = (const int*)d_in[26];
    const int* context_idx  = (const int*)d_in[27];
    float* out = (float*)d_out;

    float* wsf = (float*)d_ws;
    size_t off = 0;
    auto alloc = [&](size_t n) { size_t r = off; off += (n + 255) & ~(size_t)255; return r; };
    float* kg      = wsf + alloc(12800000);          // N*D
    float* tmp     = wsf + alloc(12800000);          // sort arena + efeat + split arenas
    ushortT* warena = (ushortT*)(wsf + alloc(196608)); // 12 x 64KB split w[r]
    int*   bsumV   = (int*)(wsf + alloc(2048));
    // ---- contiguous zero block (one memset) ----
    size_t zstart = off;
    int*   heneed  = (int*)(wsf + alloc(DHE2));
    int*   mcnt    = (int*)(wsf + alloc(16));        // [0]=sess, [1]=know
    int*   scnt    = (int*)(wsf + alloc(16));
    float* sdeg_s  = wsf + alloc(4096);
    float* sdeg_k  = wsf + alloc(4096);
    float* sacc_s  = wsf + alloc(524288);
    float* sacc_k  = wsf + alloc(524288);
    size_t zend = off;
    // ---- contiguous 0xFF block (one memset) ----
    size_t fstart = off;
    int*   slot_s  = (int*)(wsf + alloc(100000));
    int*   slot_k  = (int*)(wsf + alloc(100000));
    size_t fend = off;
    int*   pns     = (int*)(wsf + alloc(2 * DP));
    int*   mhe_s   = (int*)(wsf + alloc(MCAP));
    int*   msl_s   = (int*)(wsf + alloc(MCAP));
    int*   mhe_k   = (int*)(wsf + alloc(MCAP));
    int*   msl_k   = (int*)(wsf + alloc(MCAP));
    float* so_s    = wsf + alloc(524288);
    float* so_k    = wsf + alloc(524288);
    float* related = wsf + alloc(1048576);
    float* ctx     = wsf + alloc(262144);
    float* qb      = wsf + alloc(262144);
    float* kb      = wsf + alloc(1048576);
    float* vb      = wsf + alloc(1048576);
    float* obuf    = wsf + alloc(262144);
    float* attrel  = wsf + alloc(262144);
    float* his     = wsf + alloc(8192);
    float* ucat    = wsf + alloc(270336);
    float* userb   = wsf + alloc(8192);
    float* e1      = wsf + alloc(2048);
    float* e2      = wsf + alloc(2112);
    (void)ws_size; (void)in_sizes; (void)n_in; (void)out_size;

    // tmp arena: merged histogram/prefix (rgcn 1.2M + hyper 40K), ssrc, efeat, split arenas
    int*   hist    = (int*)tmp;                 // NALLBINS ints
    int*   soff    = (int*)tmp + 1240000;       // NALLBINS (in-place cursor during bucket)
    int*   ssrc    = (int*)tmp + 2480000;       // 1.0M
    float* efeat   = tmp + 3600000;             // 5.12M
    ushortT* wsplit = (ushortT*)(tmp + 12200000); // 9 x 32768 ushorts
    ushortT* usplit = (ushortT*)(tmp + 12400000); // 16384 ushorts

    const int nbA = (NALLBINS + SCAN_CHUNK - 1) / SCAN_CHUNK;   // 1211

    // ---------------- upfront memsets (3 total)
    hipMemsetAsync(wsf + zstart, 0, (zend - zstart) * 4, stream);
    hipMemsetAsync(wsf + fstart, 0xFF, (fend - fstart) * 4, stream);
    hipMemsetAsync(hist, 0, (size_t)NALLBINS * 4, stream);

    // weight pre-split (independent of everything else)
    k_presplit_all<<<576, 256, 0, stream>>>(root, sess_theta, know_theta, in_proj_w,
                                            out_proj_w, attn_his_a, attn_a, wsplit);

    k_slot_assign2<<<32, 256, 0, stream>>>(sess_rel_idx, know_rel_idx, slot_s, slot_k, scnt);
    k_sdeg_match<<<(DP + 255) / 256, 256, 0, stream>>>(sess_nodes, sess_edges, slot_s,
                                                       sdeg_s, mcnt, mhe_s, msl_s, heneed, 0);
    k_sdeg_match<<<(DP + 255) / 256, 256, 0, stream>>>(know_nodes, know_edges, slot_k,
                                                       sdeg_k, mcnt + 1, mhe_k, msl_k, heneed, DHE);

    // ---------------- merged histogram + single scan + merged bucket
    k_hist_both<<<(DE + 2 * DP + 255) / 256, 256, 0, stream>>>(edge_dst, edge_type, hist,
                                                               sess_edges, know_edges);
    k_scan_pass1<<<nbA, 256, 0, stream>>>(hist, NALLBINS, bsumV);
    k_scan_pass2p<<<1, 256, 0, stream>>>(bsumV, nbA, nullptr);
    k_scan_pass3<<<nbA, 256, 0, stream>>>(hist, NALLBINS, bsumV, soff);
    k_bucket_both<<<(DE + 2 * DP + 255) / 256, 256, 0, stream>>>(
        edge_src, edge_dst, edge_type, soff, ssrc,
        sess_nodes, sess_edges, know_nodes, know_edges, pns);

    k_wcomp_split<<<(DR * DD * DD + 255) / 256, 256, 0, stream>>>(comp, bases, warena);

    // ---------------- fused root + RGCN (one block per 64 dsts, non-atomic kg write)
    int gemmN = (DN + 63) / 64;
    k_rgcn_fused<<<gemmN, 256, 0, stream>>>(emb, wsplit + 0 * 32768, warena, rgcn_bias,
                                            soff, hist, ssrc, kg);

    // ---------------- hypergraph aggregation
    k_hyper_agg<<<(DHE2 * 64 + 255) / 256, 256, 0, stream>>>(kg, pns, soff + NRBINS,
                                                             hist + NRBINS, heneed, efeat);
    k_accmatch2<<<256, 256, 0, stream>>>(efeat, mhe_s, msl_s, mhe_k, msl_k, mcnt, sacc_s, sacc_k);

    k_gemm_ds<<<64, 256, 0, stream>>>(sacc_s, wsplit + 1 * 32768, sess_bias, sdeg_s,
                                      nullptr, nullptr, so_s, 4096);
    k_gemm_ds<<<64, 256, 0, stream>>>(sacc_k, wsplit + 2 * 32768, know_bias, sdeg_k,
                                      nullptr, nullptr, so_k, 4096);
    k_rel_gather2<<<(2 * DB * DLR * 32 + 255) / 256, 256, 0, stream>>>(
        so_s, so_k, slot_s, slot_k, sess_rel_idx, know_rel_idx, related);

    // ---------------- context + MHA (q-GEMM gathers ctx rows from kg and writes ctx)
    k_gemm_ds<<<(DB * DLC + 63) / 64, 256, 0, stream>>>(kg, wsplit + 3 * 32768,
                                                        in_proj_b, nullptr,
                                                        context_idx, ctx, qb, DB * DLC);
    k_gemm_ds<<<(DB * 128 + 63) / 64, 256, 0, stream>>>(related, wsplit + 4 * 32768,
                                                        in_proj_b + DD, nullptr,
                                                        nullptr, nullptr, kb, DB * 128);
    k_gemm_ds<<<(DB * 128 + 63) / 64, 256, 0, stream>>>(related, wsplit + 5 * 32768,
                                                        in_proj_b + 2 * DD, nullptr,
                                                        nullptr, nullptr, vb, DB * 128);
    k_mha<<<DB * DNH, 256, 0, stream>>>(qb, kb, vb, obuf);
    k_gemm_ds<<<(DB * DLC + 63) / 64, 256, 0, stream>>>(obuf, wsplit + 6 * 32768,
                                                        out_proj_b, nullptr,
                                                        nullptr, nullptr, attrel, DB * DLC);

    // ---------------- pooling (GEMM-shaped) + score
    k_tanh_dot_ds<<<(DB * DLC + 63) / 64, 256, 0, stream>>>(attrel, wsplit + 7 * 32768,
                                                            attn_his_b, e1, DB * DLC);
    k_pool_apply<32><<<DB, 128, 0, stream>>>(attrel, e1, his, nullptr);
    k_build_ucat<<<(DB * 33 * 128 + 255) / 256, 256, 0, stream>>>(ctx, his, ucat);
    k_tanh_dot_ds<<<(DB * 33 + 63) / 64, 256, 0, stream>>>(ucat, wsplit + 8 * 32768,
                                                           attn_b, e2, DB * 33);
    k_pool_apply<33><<<DB, 128, 0, stream>>>(ucat, e2, userb, usplit);
    k_score_ds<<<gemmN, 256, 0, stream>>>(kg, usplit, rec_bias, out);
}

// Round 6
// 943.268 us; speedup vs baseline: 2.1047x; 2.1047x over previous
//
#include <hip/hip_runtime.h>
#include <hip/hip_bf16.h>

#define DN 100000     // N entities
#define DD 128        // D
#define DR 12         // R relations
#define DNB 8         // bases
#define DE 1000000    // edges
#define DP 400000     // hyperedge incidences
#define DHE 20000     // hyperedges
#define DHE2 40000    // both sides combined
#define DB 64         // batch
#define DLR 64
#define DLC 32
#define DNH 8
#define DHD 16
#define NRBINS (DR * DN)   // 1.2M
#define NALLBINS (NRBINS + DHE2)
#define SCAN_CHUNK 1024
#define MCAP 65536

typedef unsigned short ushortT;
typedef unsigned int uintT;
typedef __attribute__((ext_vector_type(8))) short s8v;
typedef __attribute__((ext_vector_type(4))) float f4v;

#define APAD 136   // bf16 LDS row stride for 128-K tiles (272B)
#define ASLB 40    // bf16 LDS row stride for 32-K slabs (80B, 16B-aligned, ~2-way banks)

__device__ __forceinline__ ushortT rneb(float v) {
    uintT b = __float_as_uint(v);
    return (ushortT)((b + 0x7FFFu + ((b >> 16) & 1u)) >> 16);
}
__device__ __forceinline__ float b2f(ushortT h) {
    return __uint_as_float(((uintT)h) << 16);
}

__device__ __forceinline__ void split_store8(ushortT* hbase, ushortT* lbase, const float* v)
{
    ushortT h[8], l[8];
    #pragma unroll
    for (int j = 0; j < 8; ++j) {
        h[j] = rneb(v[j]);
        l[j] = rneb(v[j] - b2f(h[j]));
    }
    uint4 hv = make_uint4((uintT)h[0] | ((uintT)h[1] << 16), (uintT)h[2] | ((uintT)h[3] << 16),
                          (uintT)h[4] | ((uintT)h[5] << 16), (uintT)h[6] | ((uintT)h[7] << 16));
    uint4 lv = make_uint4((uintT)l[0] | ((uintT)l[1] << 16), (uintT)l[2] | ((uintT)l[3] << 16),
                          (uintT)l[4] | ((uintT)l[5] << 16), (uintT)l[6] | ((uintT)l[7] << 16));
    *(uint4*)hbase = hv;
    *(uint4*)lbase = lv;
}

// ---------------------------------------------------------------- weight pre-split (blocked fragment layout)
// WB[kc][n][k] ushort, h plane then l plane at +16384.
// 0 root(t0) 1 sess_theta(t0) 2 know_theta(t0) 3 wq(t1) 4 wk(t1) 5 wv(t1)
// 6 out_proj(t1) 7 attn_his_a(t0) 8 attn_a(t0)
__global__ __launch_bounds__(256) void k_presplit_all(
    const float* __restrict__ root, const float* __restrict__ st,
    const float* __restrict__ kt, const float* __restrict__ ipw,
    const float* __restrict__ opw, const float* __restrict__ aha,
    const float* __restrict__ aa, ushortT* __restrict__ outA)
{
    int gid = blockIdx.x * 256 + threadIdx.x;   // 9*16384 exact
    int mat = gid >> 14, e = gid & 16383;
    const float* srcs[9] = {root, st, kt, ipw, ipw + 16384, ipw + 32768, opw, aha, aa};
    const float* W = srcs[mat];
    bool t1 = (mat >= 3 && mat <= 6);
    int k = e & 31, n = (e >> 5) & 127, kc = e >> 12;
    float f = t1 ? W[(size_t)n * 128 + kc * 32 + k] : W[(size_t)(kc * 32 + k) * 128 + n];
    ushortT h = rneb(f);
    outA[(size_t)mat * 32768 + e] = h;
    outA[(size_t)mat * 32768 + 16384 + e] = rneb(f - b2f(h));
}

// w[r] = comp[r]·bases, split directly into blocked layout (64KB per r: h 32KB, l 32KB)
__global__ void k_wcomp_split(const float* __restrict__ comp, const float* __restrict__ bases,
                              ushortT* __restrict__ warena)
{
    int i = blockIdx.x * blockDim.x + threadIdx.x;
    if (i >= DR * DD * DD) return;
    int r = i / (DD * DD), io = i % (DD * DD);
    float s = 0.f;
    #pragma unroll
    for (int b = 0; b < DNB; ++b) s += comp[r * DNB + b] * bases[(size_t)b * DD * DD + io];
    int irow = io >> 7, o = io & 127;          // irow = k-dim
    int kc = irow >> 5, k = irow & 31;
    size_t dst = (size_t)r * 32768 + (size_t)kc * 4096 + o * 32 + k;
    ushortT h = rneb(s);
    warena[dst] = h;
    warena[dst + 16384] = rneb(s - b2f(h));
}

// ---------------------------------------------------------------- MFMA GEMM, B copy-staged per kc from pre-split global
__global__ __launch_bounds__(256) void k_gemm_ds(
    const float* __restrict__ A, const ushortT* __restrict__ Wb,
    const float* __restrict__ bias, const float* __restrict__ rs,
    const int* __restrict__ gidx, float* __restrict__ gout,
    float* __restrict__ C, int M)
{
    __shared__ __align__(16) ushortT Ah[64 * APAD], Al[64 * APAD];
    __shared__ __align__(16) ushortT Bs[8192];
    int tid = threadIdx.x;
    int row0 = blockIdx.x * 64;
    {
        int row = tid >> 2, c0 = (tid & 3) * 32;
        int gr = row0 + row;
        int arow = gr;
        if (gidx && gr < M) arow = gidx[gr];
        const float* ar = A + (size_t)arow * 128 + c0;
        float sc = 1.0f;
        if (rs && gr < M) { float d = rs[gr]; sc = (d > 0.f) ? 1.0f / d : 0.f; }
        #pragma unroll
        for (int g = 0; g < 4; ++g) {
            float v[8] = {};
            if (gr < M) {
                float4 u0 = *(const float4*)(ar + g * 8);
                float4 u1 = *(const float4*)(ar + g * 8 + 4);
                v[0]=u0.x*sc; v[1]=u0.y*sc; v[2]=u0.z*sc; v[3]=u0.w*sc;
                v[4]=u1.x*sc; v[5]=u1.y*sc; v[6]=u1.z*sc; v[7]=u1.w*sc;
                if (gout) {
                    *(float4*)(gout + (size_t)gr * 128 + c0 + g * 8)     = u0;
                    *(float4*)(gout + (size_t)gr * 128 + c0 + g * 8 + 4) = u1;
                }
            }
            split_store8(&Ah[row * APAD + c0 + g * 8], &Al[row * APAD + c0 + g * 8], v);
        }
    }
    f4v acc[8] = {};
    int w = tid >> 6, lane = tid & 63, m = lane & 15, quad = lane >> 4;
    for (int kc = 0; kc < 4; ++kc) {
        __syncthreads();
        {
            const ushortT* gh = Wb + kc * 4096;
            const ushortT* gl = Wb + 16384 + kc * 4096;
            *(s8v*)&Bs[tid * 8]        = *(const s8v*)&gh[tid * 8];
            *(s8v*)&Bs[2048 + tid * 8] = *(const s8v*)&gh[2048 + tid * 8];
            *(s8v*)&Bs[4096 + tid * 8] = *(const s8v*)&gl[tid * 8];
            *(s8v*)&Bs[6144 + tid * 8] = *(const s8v*)&gl[2048 + tid * 8];
        }
        __syncthreads();
        s8v ah = *(const s8v*)&Ah[(w * 16 + m) * APAD + kc * 32 + quad * 8];
        s8v al = *(const s8v*)&Al[(w * 16 + m) * APAD + kc * 32 + quad * 8];
        #pragma unroll
        for (int nt = 0; nt < 8; ++nt) {
            int boff = (nt * 16 + m) * 32 + quad * 8;
            s8v bh = *(const s8v*)&Bs[boff];
            s8v bl = *(const s8v*)&Bs[4096 + boff];
            acc[nt] = __builtin_amdgcn_mfma_f32_16x16x32_bf16(ah, bh, acc[nt], 0, 0, 0);
            acc[nt] = __builtin_amdgcn_mfma_f32_16x16x32_bf16(al, bh, acc[nt], 0, 0, 0);
            acc[nt] = __builtin_amdgcn_mfma_f32_16x16x32_bf16(ah, bl, acc[nt], 0, 0, 0);
        }
    }
    float bv[8];
    #pragma unroll
    for (int nt = 0; nt < 8; ++nt) bv[nt] = bias ? bias[nt * 16 + m] : 0.f;
    #pragma unroll
    for (int rr = 0; rr < 4; ++rr) {
        int gr = row0 + w * 16 + quad * 4 + rr;
        if (gr < M) {
            #pragma unroll
            for (int nt = 0; nt < 8; ++nt)
                C[(size_t)gr * 128 + nt * 16 + m] = acc[nt][rr] + bv[nt];
        }
    }
}

// ---------------------------------------------------------------- fused e[row] = tanh(A@W)[row,:] . bvec
__global__ __launch_bounds__(256) void k_tanh_dot_ds(
    const float* __restrict__ A, const ushortT* __restrict__ Wb,
    const float* __restrict__ bvec, float* __restrict__ e, int M)
{
    __shared__ __align__(16) ushortT Ah[64 * APAD], Al[64 * APAD];
    __shared__ __align__(16) ushortT Bs[8192];
    int tid = threadIdx.x;
    int row0 = blockIdx.x * 64;
    {
        int row = tid >> 2, c0 = (tid & 3) * 32;
        int gr = row0 + row;
        const float* ar = A + (size_t)gr * 128 + c0;
        #pragma unroll
        for (int g = 0; g < 4; ++g) {
            float v[8] = {};
            if (gr < M) {
                float4 u0 = *(const float4*)(ar + g * 8);
                float4 u1 = *(const float4*)(ar + g * 8 + 4);
                v[0]=u0.x; v[1]=u0.y; v[2]=u0.z; v[3]=u0.w;
                v[4]=u1.x; v[5]=u1.y; v[6]=u1.z; v[7]=u1.w;
            }
            split_store8(&Ah[row * APAD + c0 + g * 8], &Al[row * APAD + c0 + g * 8], v);
        }
    }
    f4v acc[8] = {};
    int w = tid >> 6, lane = tid & 63, m = lane & 15, quad = lane >> 4;
    for (int kc = 0; kc < 4; ++kc) {
        __syncthreads();
        {
            const ushortT* gh = Wb + kc * 4096;
            const ushortT* gl = Wb + 16384 + kc * 4096;
            *(s8v*)&Bs[tid * 8]        = *(const s8v*)&gh[tid * 8];
            *(s8v*)&Bs[2048 + tid * 8] = *(const s8v*)&gh[2048 + tid * 8];
            *(s8v*)&Bs[4096 + tid * 8] = *(const s8v*)&gl[tid * 8];
            *(s8v*)&Bs[6144 + tid * 8] = *(const s8v*)&gl[2048 + tid * 8];
        }
        __syncthreads();
        s8v ah = *(const s8v*)&Ah[(w * 16 + m) * APAD + kc * 32 + quad * 8];
        s8v al = *(const s8v*)&Al[(w * 16 + m) * APAD + kc * 32 + quad * 8];
        #pragma unroll
        for (int nt = 0; nt < 8; ++nt) {
            int boff = (nt * 16 + m) * 32 + quad * 8;
            s8v bh = *(const s8v*)&Bs[boff];
            s8v bl = *(const s8v*)&Bs[4096 + boff];
            acc[nt] = __builtin_amdgcn_mfma_f32_16x16x32_bf16(ah, bh, acc[nt], 0, 0, 0);
            acc[nt] = __builtin_amdgcn_mfma_f32_16x16x32_bf16(al, bh, acc[nt], 0, 0, 0);
            acc[nt] = __builtin_amdgcn_mfma_f32_16x16x32_bf16(ah, bl, acc[nt], 0, 0, 0);
        }
    }
    float bv[8];
    #pragma unroll
    for (int nt = 0; nt < 8; ++nt) bv[nt] = bvec[nt * 16 + m];
    #pragma unroll
    for (int rr = 0; rr < 4; ++rr) {
        float p = 0.f;
        #pragma unroll
        for (int nt = 0; nt < 8; ++nt) p += tanhf(acc[nt][rr]) * bv[nt];
        #pragma unroll
        for (int o = 1; o < 16; o <<= 1) p += __shfl_xor(p, o);
        int gr = row0 + w * 16 + quad * 4 + rr;
        if (m == 0 && gr < M) e[gr] = p;
    }
}

// ---------------------------------------------------------------- softmax(e) weighted sum of h rows (+ optional user split)
template <int L>
__global__ __launch_bounds__(128) void k_pool_apply(const float* __restrict__ h,
                                                    const float* __restrict__ e,
                                                    float* __restrict__ out,
                                                    ushortT* __restrict__ us)
{
    __shared__ float es[L];
    int b = blockIdx.x, tid = threadIdx.x;
    if (tid < L) es[tid] = e[b * L + tid];
    __syncthreads();
    float mx = -1e30f;
    #pragma unroll
    for (int l = 0; l < L; ++l) mx = fmaxf(mx, es[l]);
    float wgt[L];
    float sum = 0.f;
    #pragma unroll
    for (int l = 0; l < L; ++l) { wgt[l] = __expf(es[l] - mx); sum += wgt[l]; }
    float inv = 1.0f / sum;
    float o = 0.f;
    #pragma unroll
    for (int l = 0; l < L; ++l) o += wgt[l] * h[((size_t)b * L + l) * 128 + tid];
    float val = o * inv;
    out[(size_t)b * 128 + tid] = val;
    if (us) {
        ushortT hh = rneb(val);
        ushortT ll = rneb(val - b2f(hh));
        int e_ = ((tid >> 5) * 2048) + b * 32 + (tid & 31);
        us[e_] = hh;
        us[8192 + e_] = ll;
    }
}

__global__ void k_build_ucat(const float* __restrict__ ctx, const float* __restrict__ his,
                             float* ucat)
{
    int i = blockIdx.x * blockDim.x + threadIdx.x;
    if (i >= DB * 33 * 128) return;
    int d = i & 127, l = (i >> 7) % 33, b = i / (33 * 128);
    ucat[i] = (l < 32) ? ctx[((size_t)b * 32 + l) * 128 + d] : his[(size_t)b * 128 + d];
}

// ---------------------------------------------------------------- fused root + RGCN, stacked-K formulation.
// One block owns 64 dsts. kg[dst] = [x[dst] | mean_0 | ... | mean_11] @ [root; w_0; ...; w_11] + bias.
// 52 K-slabs of 32; A-slab staged per-slab (serial per-thread gather, no LDS atomics);
// warena's r-major layout IS the stacked B. One non-atomic 512B write per dst.
__global__ __launch_bounds__(256) void k_rgcn_fk(
    const float* __restrict__ x, const ushortT* __restrict__ rootsplit,
    const ushortT* __restrict__ warena, const float* __restrict__ bias,
    const int* __restrict__ soff, const int* __restrict__ hist,
    const int* __restrict__ ssrc, float* __restrict__ kg)
{
    __shared__ __align__(16) ushortT Ah[64 * ASLB], Al[64 * ASLB];
    __shared__ __align__(16) ushortT Bs[8192];
    int tid = threadIdx.x;
    int dst0 = blockIdx.x * 64;
    int nrow = min(64, DN - dst0);
    int w = tid >> 6, lane = tid & 63, m = lane & 15, quad = lane >> 4;
    int row = tid >> 2, ci = (tid & 3) * 8;
    f4v acc[8] = {};

    for (int s = 0; s < 52; ++s) {
        int r = (s - 4) >> 2, kci = (s - 4) & 3;
        __syncthreads();   // previous slab's LDS reads complete
        // ---- stage A slab [64][32]: thread covers (row, ci..ci+8)
        {
            float a[8] = {};
            if (row < nrow) {
                if (s < 4) {
                    const float* ar = x + (size_t)(dst0 + row) * 128 + s * 32 + ci;
                    float4 u0 = *(const float4*)ar, u1 = *(const float4*)(ar + 4);
                    a[0]=u0.x; a[1]=u0.y; a[2]=u0.z; a[3]=u0.w;
                    a[4]=u1.x; a[5]=u1.y; a[6]=u1.z; a[7]=u1.w;
                } else {
                    int key = (dst0 + row) * DR + r;
                    int len = hist[key];
                    int st = soff[key] - len;   // soff is in-place inclusive end after bucketing
                    int cb = kci * 32 + ci;
                    for (int i = 0; i < len; ++i) {
                        const float* xr = x + (size_t)ssrc[st + i] * 128 + cb;
                        float4 v0 = *(const float4*)xr, v1 = *(const float4*)(xr + 4);
                        a[0]+=v0.x; a[1]+=v0.y; a[2]+=v0.z; a[3]+=v0.w;
                        a[4]+=v1.x; a[5]+=v1.y; a[6]+=v1.z; a[7]+=v1.w;
                    }
                    float inv = (len > 0) ? 1.0f / (float)len : 0.f;
                    #pragma unroll
                    for (int j = 0; j < 8; ++j) a[j] *= inv;
                }
            }
            split_store8(&Ah[row * ASLB + ci], &Al[row * ASLB + ci], a);
        }
        // ---- stage B slab [128][32] h+l (pure copy, 16KB)
        {
            const ushortT* bb = (s < 4) ? rootsplit + s * 4096
                                        : warena + (size_t)r * 32768 + kci * 4096;
            const ushortT* bl = (s < 4) ? rootsplit + 16384 + s * 4096
                                        : warena + (size_t)r * 32768 + 16384 + kci * 4096;
            *(s8v*)&Bs[tid * 8]        = *(const s8v*)&bb[tid * 8];
            *(s8v*)&Bs[2048 + tid * 8] = *(const s8v*)&bb[2048 + tid * 8];
            *(s8v*)&Bs[4096 + tid * 8] = *(const s8v*)&bl[tid * 8];
            *(s8v*)&Bs[6144 + tid * 8] = *(const s8v*)&bl[2048 + tid * 8];
        }
        __syncthreads();
        s8v ah = *(const s8v*)&Ah[(w * 16 + m) * ASLB + quad * 8];
        s8v al = *(const s8v*)&Al[(w * 16 + m) * ASLB + quad * 8];
        #pragma unroll
        for (int nt = 0; nt < 8; ++nt) {
            int boff = (nt * 16 + m) * 32 + quad * 8;
            s8v bh = *(const s8v*)&Bs[boff];
            s8v bl2 = *(const s8v*)&Bs[4096 + boff];
            acc[nt] = __builtin_amdgcn_mfma_f32_16x16x32_bf16(ah, bh, acc[nt], 0, 0, 0);
            acc[nt] = __builtin_amdgcn_mfma_f32_16x16x32_bf16(al, bh, acc[nt], 0, 0, 0);
            acc[nt] = __builtin_amdgcn_mfma_f32_16x16x32_bf16(ah, bl2, acc[nt], 0, 0, 0);
        }
    }
    float bv[8];
    #pragma unroll
    for (int nt = 0; nt < 8; ++nt) bv[nt] = bias[nt * 16 + m];
    #pragma unroll
    for (int rr = 0; rr < 4; ++rr) {
        int gr = dst0 + w * 16 + quad * 4 + rr;
        if (gr < DN) {
            #pragma unroll
            for (int nt = 0; nt < 8; ++nt)
                kg[(size_t)gr * 128 + nt * 16 + m] = acc[nt][rr] + bv[nt];
        }
    }
}

// ---------------------------------------------------------------- scoring (MFMA, B copy-staged from pre-split user)
__global__ __launch_bounds__(256) void k_score_ds(
    const float* __restrict__ kg, const ushortT* __restrict__ Ub,
    const float* __restrict__ rb, float* __restrict__ out)
{
    __shared__ __align__(16) ushortT Ah[64 * APAD], Al[64 * APAD];
    __shared__ __align__(16) ushortT Bs[4096];
    int tid = threadIdx.x;
    int n0 = blockIdx.x * 64;
    {
        int row = tid >> 2, c0 = (tid & 3) * 32;
        int gr = n0 + row;
        const float* ar = kg + (size_t)gr * 128 + c0;
        #pragma unroll
        for (int g = 0; g < 4; ++g) {
            float v[8] = {};
            if (gr < DN) {
                float4 u0 = *(const float4*)(ar + g * 8);
                float4 u1 = *(const float4*)(ar + g * 8 + 4);
                v[0]=u0.x; v[1]=u0.y; v[2]=u0.z; v[3]=u0.w;
                v[4]=u1.x; v[5]=u1.y; v[6]=u1.z; v[7]=u1.w;
            }
            split_store8(&Ah[row * APAD + c0 + g * 8], &Al[row * APAD + c0 + g * 8], v);
        }
    }
    f4v acc[4] = {};
    int w = tid >> 6, lane = tid & 63, m = lane & 15, quad = lane >> 4;
    for (int kc = 0; kc < 4; ++kc) {
        __syncthreads();
        {
            const ushortT* gh = Ub + kc * 2048;
            const ushortT* gl = Ub + 8192 + kc * 2048;
            *(s8v*)&Bs[tid * 8]        = *(const s8v*)&gh[tid * 8];
            *(s8v*)&Bs[2048 + tid * 8] = *(const s8v*)&gl[tid * 8];
        }
        __syncthreads();
        s8v ah = *(const s8v*)&Ah[(w * 16 + m) * APAD + kc * 32 + quad * 8];
        s8v al = *(const s8v*)&Al[(w * 16 + m) * APAD + kc * 32 + quad * 8];
        #pragma unroll
        for (int nt = 0; nt < 4; ++nt) {
            int boff = (nt * 16 + m) * 32 + quad * 8;
            s8v bh = *(const s8v*)&Bs[boff];
            s8v bl = *(const s8v*)&Bs[2048 + boff];
            acc[nt] = __builtin_amdgcn_mfma_f32_16x16x32_bf16(ah, bh, acc[nt], 0, 0, 0);
            acc[nt] = __builtin_amdgcn_mfma_f32_16x16x32_bf16(al, bh, acc[nt], 0, 0, 0);
            acc[nt] = __builtin_amdgcn_mfma_f32_16x16x32_bf16(ah, bl, acc[nt], 0, 0, 0);
        }
    }
    int n = n0 + w * 16 + quad * 4;
    if (n < DN) {
        float4 rbv = *(const float4*)&rb[n];
        #pragma unroll
        for (int nt = 0; nt < 4; ++nt) {
            int b = nt * 16 + m;
            float4 o = make_float4(acc[nt][0] + rbv.x, acc[nt][1] + rbv.y,
                                   acc[nt][2] + rbv.z, acc[nt][3] + rbv.w);
            *(float4*)&out[(size_t)b * DN + n] = o;
        }
    }
}

// ---------------------------------------------------------------- scans (single merged array: rgcn bins + hyper bins)
__global__ void k_scan_pass1(const int* __restrict__ in, int n, int* __restrict__ bsum)
{
    __shared__ int red[256];
    int b = blockIdx.x, t = threadIdx.x;
    int i0 = b * SCAN_CHUNK + t * 4;
    int s = 0;
    #pragma unroll
    for (int j = 0; j < 4; ++j) {
        int i = i0 + j;
        if (i < n) s += in[i];
    }
    red[t] = s;
    __syncthreads();
    for (int o = 128; o > 0; o >>= 1) {
        if (t < o) red[t] += red[t + o];
        __syncthreads();
    }
    if (t == 0) bsum[b] = red[0];
}

__global__ __launch_bounds__(256) void k_scan_pass2p(int* bsum, int nb, int* total)
{
    __shared__ int lds[256];
    __shared__ int carry;
    int t = threadIdx.x;
    if (t == 0) carry = 0;
    __syncthreads();
    for (int c0 = 0; c0 < nb; c0 += 256) {
        int i = c0 + t;
        int v = (i < nb) ? bsum[i] : 0;
        lds[t] = v;
        __syncthreads();
        for (int o = 1; o < 256; o <<= 1) {
            int add = (t >= o) ? lds[t - o] : 0;
            __syncthreads();
            lds[t] += add;
            __syncthreads();
        }
        int myc = carry;
        if (i < nb) bsum[i] = lds[t] - v + myc;
        int tot = lds[255];
        __syncthreads();
        if (t == 0) carry = myc + tot;
        __syncthreads();
    }
    if (total && t == 0) *total = carry;
}

__global__ void k_scan_pass3(const int* __restrict__ in, int n, const int* __restrict__ bsum,
                             int* __restrict__ out)
{
    __shared__ int lds[256];
    int b = blockIdx.x, t = threadIdx.x;
    int i0 = b * SCAN_CHUNK + t * 4;
    int v[4]; int s = 0;
    #pragma unroll
    for (int j = 0; j < 4; ++j) {
        int i = i0 + j;
        int x = 0;
        if (i < n) x = in[i];
        v[j] = x; s += x;
    }
    lds[t] = s;
    __syncthreads();
    for (int o = 1; o < 256; o <<= 1) {
        int add = (t >= o) ? lds[t - o] : 0;
        __syncthreads();
        lds[t] += add;
        __syncthreads();
    }
    int run = lds[t] - s + bsum[b];
    #pragma unroll
    for (int j = 0; j < 4; ++j) {
        int i = i0 + j;
        if (i < n) { out[i] = run; run += v[j]; }
    }
}

// ---------------------------------------------------------------- merged histogram (RGCN key = dst*DR + et; hyper at +NRBINS)
__global__ void k_hist_both(const int* __restrict__ dst, const int* __restrict__ et,
                            int* __restrict__ hist,
                            const int* __restrict__ se, const int* __restrict__ ke)
{
    int i = blockIdx.x * blockDim.x + threadIdx.x;
    if (i < DE) {
        atomicAdd(&hist[dst[i] * DR + et[i]], 1);
    } else {
        int j = i - DE;
        if (j < DP) atomicAdd(&hist[NRBINS + se[j]], 1);
        else if (j < 2 * DP) atomicAdd(&hist[NRBINS + DHE + ke[j - DP]], 1);
    }
}

// merged bucket scatter (in-place cursor). Hyper positions are offset by DE (concat prefix) -> pns[pos-DE].
__global__ void k_bucket_both(const int* __restrict__ src, const int* __restrict__ dst,
                              const int* __restrict__ et, int* __restrict__ soff,
                              int* __restrict__ ssrc,
                              const int* __restrict__ sn, const int* __restrict__ se,
                              const int* __restrict__ kn, const int* __restrict__ ke,
                              int* __restrict__ pns)
{
    int i = blockIdx.x * blockDim.x + threadIdx.x;
    if (i < DE) {
        int key = dst[i] * DR + et[i];
        int pos = atomicAdd(&soff[key], 1);
        ssrc[pos] = src[i];
    } else {
        int j = i - DE;
        if (j >= 2 * DP) return;
        int e, node;
        if (j < DP) { e = se[j]; node = sn[j]; }
        else { e = DHE + ke[j - DP]; node = kn[j - DP]; }
        int pos = atomicAdd(&soff[NRBINS + e], 1);
        pns[pos - DE] = node;
    }
}

// one wave per NEEDED hyperedge; st from in-place cursor (minus DE concat offset)
__global__ void k_hyper_agg(const float* __restrict__ xsrc, const int* __restrict__ pns,
                            const int* __restrict__ hoff, const int* __restrict__ hcnt,
                            const int* __restrict__ heneed, float* __restrict__ efeat)
{
    int lane = threadIdx.x & 63;
    int he = (blockIdx.x * blockDim.x + threadIdx.x) >> 6;
    if (he >= DHE2) return;
    if (!heneed[he]) return;
    int len = hcnt[he];
    int st = hoff[he] - len - DE;
    int half = lane >> 5;
    int c16 = (lane & 31) * 4;
    float4 acc = make_float4(0.f, 0.f, 0.f, 0.f);
    int c = 0;
    for (; c + 4 <= len; c += 4) {
        int n0 = pns[st + c + half];
        int n1 = pns[st + c + 2 + half];
        float4 v0 = *(const float4*)&xsrc[(size_t)n0 * 128 + c16];
        float4 v1 = *(const float4*)&xsrc[(size_t)n1 * 128 + c16];
        acc.x += v0.x + v1.x; acc.y += v0.y + v1.y;
        acc.z += v0.z + v1.z; acc.w += v0.w + v1.w;
    }
    for (; c < len; c += 2) {
        int idx = c + half;
        if (idx < len) {
            int n = pns[st + idx];
            float4 v = *(const float4*)&xsrc[(size_t)n * 128 + c16];
            acc.x += v.x; acc.y += v.y; acc.z += v.z; acc.w += v.w;
        }
    }
    acc.x += __shfl_xor(acc.x, 32);
    acc.y += __shfl_xor(acc.y, 32);
    acc.z += __shfl_xor(acc.z, 32);
    acc.w += __shfl_xor(acc.w, 32);
    if (half == 0) {
        float inv = (len > 0) ? 1.0f / (float)len : 0.f;
        float4 o = make_float4(acc.x * inv, acc.y * inv, acc.z * inv, acc.w * inv);
        *(float4*)&efeat[(size_t)he * 128 + c16] = o;
    }
}

__global__ void k_slot_assign2(const int* __restrict__ sidx, const int* __restrict__ kidx,
                               int* slot_s, int* slot_k, int* scnt)
{
    int i = blockIdx.x * blockDim.x + threadIdx.x;
    if (i < DB * DLR) {
        int node = sidx[i];
        if (atomicCAS(&slot_s[node], -1, -2) == -1) slot_s[node] = atomicAdd(&scnt[0], 1);
    } else if (i < 2 * DB * DLR) {
        int node = kidx[i - DB * DLR];
        if (atomicCAS(&slot_k[node], -1, -2) == -1) slot_k[node] = atomicAdd(&scnt[1], 1);
    }
}

// fused sdeg + match + need-flag, block-aggregated compaction
__global__ __launch_bounds__(256) void k_sdeg_match(
    const int* __restrict__ nodes, const int* __restrict__ he, const int* __restrict__ slot,
    float* sdeg, int* mcnt, int* mhe, int* msl, int* heneed, int heBase)
{
    __shared__ int lcnt, lbase;
    if (threadIdx.x == 0) lcnt = 0;
    __syncthreads();
    int i = blockIdx.x * 256 + threadIdx.x;
    int s = -1, lidx = 0, h = 0;
    if (i < DP) {
        s = slot[nodes[i]];
        if (s >= 0) {
            h = heBase + he[i];
            heneed[h] = 1;
            atomicAdd(&sdeg[s], 1.0f);
            lidx = atomicAdd(&lcnt, 1);
        }
    }
    __syncthreads();
    if (threadIdx.x == 0) lbase = (lcnt > 0) ? atomicAdd(mcnt, lcnt) : 0;
    __syncthreads();
    if (s >= 0) {
        int idx = lbase + lidx;
        if (idx < MCAP) { mhe[idx] = h; msl[idx] = s; }
    }
}

// both sides in one launch
__global__ void k_accmatch2(const float* __restrict__ efeat,
                            const int* __restrict__ mhe_s, const int* __restrict__ msl_s,
                            const int* __restrict__ mhe_k, const int* __restrict__ msl_k,
                            const int* __restrict__ mcnt,
                            float* sacc_s, float* sacc_k)
{
    int lane = threadIdx.x & 63;
    int w = (blockIdx.x * blockDim.x + threadIdx.x) >> 6;
    int nw = (gridDim.x * blockDim.x) >> 6;
    int Ms = min(mcnt[0], MCAP), Mk = min(mcnt[1], MCAP);
    for (int i = w; i < Ms + Mk; i += nw) {
        bool sess = i < Ms;
        int he = sess ? mhe_s[i] : mhe_k[i - Ms];
        int sl = sess ? msl_s[i] : msl_k[i - Ms];
        float* sacc = sess ? sacc_s : sacc_k;
        float2 v = *(const float2*)&efeat[(size_t)he * 128 + lane * 2];
        atomicAdd(&sacc[(size_t)sl * 128 + lane * 2],     v.x);
        atomicAdd(&sacc[(size_t)sl * 128 + lane * 2 + 1], v.y);
    }
}

// both sides in one launch
__global__ void k_rel_gather2(const float* __restrict__ so_s, const float* __restrict__ so_k,
                              const int* __restrict__ slot_s, const int* __restrict__ slot_k,
                              const int* __restrict__ ridx_s, const int* __restrict__ ridx_k,
                              float* __restrict__ related)
{
    int gid = blockIdx.x * blockDim.x + threadIdx.x;
    int i = gid >> 5, c = gid & 31;
    if (i >= 2 * DB * DLR) return;
    bool sess = i < DB * DLR;
    int ii = sess ? i : i - DB * DLR;
    int s = sess ? slot_s[ridx_s[ii]] : slot_k[ridx_k[ii]];
    const float* so = sess ? so_s : so_k;
    int b = ii / DLR, l = ii % DLR;
    int colOff = sess ? 0 : 64;
    ((float4*)&related[((size_t)b * 128 + colOff + l) * 128])[c] =
        ((const float4*)&so[(size_t)s * 128])[c];
}

// ---------------------------------------------------------------- MHA: one block per (b,h)
__global__ __launch_bounds__(256) void k_mha(const float* __restrict__ qb,
                                             const float* __restrict__ kb,
                                             const float* __restrict__ vb,
                                             float* __restrict__ ob)
{
    int b = blockIdx.x >> 3, h = blockIdx.x & 7;
    __shared__ float Ks[128][16], Vs[128][16], Qs[32][16];
    int tid = threadIdx.x;
    for (int i = tid; i < 128 * 16; i += 256) {
        int j = i >> 4, d = i & 15;
        Ks[j][d] = kb[((size_t)b * 128 + j) * 128 + h * 16 + d];
        Vs[j][d] = vb[((size_t)b * 128 + j) * 128 + h * 16 + d];
    }
    for (int i = tid; i < 32 * 16; i += 256) {
        int q = i >> 4, d = i & 15;
        Qs[q][d] = qb[((size_t)b * 32 + q) * 128 + h * 16 + d] * 0.25f;
    }
    __syncthreads();
    int q = tid >> 3;
    int jg = tid & 7;
    float lg[16];
    float m = -1e30f;
    #pragma unroll
    for (int jj = 0; jj < 16; ++jj) {
        int j = jg * 16 + jj;
        float s = 0.f;
        #pragma unroll
        for (int d = 0; d < 16; ++d) s += Qs[q][d] * Ks[j][d];
        lg[jj] = s;
        m = fmaxf(m, s);
    }
    #pragma unroll
    for (int o = 1; o < 8; o <<= 1) m = fmaxf(m, __shfl_xor(m, o));
    float sum = 0.f;
    float acc[16] = {};
    #pragma unroll
    for (int jj = 0; jj < 16; ++jj) {
        float p = __expf(lg[jj] - m);
        sum += p;
        int j = jg * 16 + jj;
        #pragma unroll
        for (int d = 0; d < 16; ++d) acc[d] += p * Vs[j][d];
    }
    #pragma unroll
    for (int o = 1; o < 8; o <<= 1) {
        sum += __shfl_xor(sum, o);
        #pragma unroll
        for (int d = 0; d < 16; ++d) acc[d] += __shfl_xor(acc[d], o);
    }
    if (jg == 0) {
        float inv = 1.0f / sum;
        #pragma unroll
        for (int d = 0; d < 16; ++d)
            ob[((size_t)b * 32 + q) * 128 + h * 16 + d] = acc[d] * inv;
    }
}

// ---------------------------------------------------------------- launch
extern "C" void kernel_launch(void* const* d_in, const int* in_sizes, int n_in,
                              void* d_out, int out_size, void* d_ws, size_t ws_size,
                              hipStream_t stream)
{
    const float* emb        = (const float*)d_in[0];
    const float* bases      = (const float*)d_in[1];
    const float* comp       = (const float*)d_in[2];
    const float* root       = (const float*)d_in[3];
    const float* rgcn_bias  = (const float*)d_in[4];
    const float* sess_theta = (const float*)d_in[5];
    const float* sess_bias  = (const float*)d_in[6];
    const float* know_theta = (const float*)d_in[7];
    const float* know_bias  = (const float*)d_in[8];
    const float* in_proj_w  = (const float*)d_in[9];
    const float* in_proj_b  = (const float*)d_in[10];
    const float* out_proj_w = (const float*)d_in[11];
    const float* out_proj_b = (const float*)d_in[12];
    const float* attn_his_a = (const float*)d_in[13];
    const float* attn_his_b = (const float*)d_in[14];
    const float* attn_a     = (const float*)d_in[15];
    const float* attn_b     = (const float*)d_in[16];
    const float* rec_bias   = (const float*)d_in[17];
    const int* edge_src     = (const int*)d_in[18];
    const int* edge_dst     = (const int*)d_in[19];
    const int* edge_type    = (const int*)d_in[20];
    const int* sess_nodes   = (const int*)d_in[21];
    const int* sess_edges   = (const int*)d_in[22];
    const int* know_nodes   = (const int*)d_in[23];
    const int* know_edges   = (const int*)d_in[24];
    const int* sess_rel_idx = (const int*)d_in[25];
    const int* know_rel_idx = (const int*)d_in[26];
    const int* context_idx  = (const int*)d_in[27];
    float* out = (float*)d_out;

    float* wsf = (float*)d_ws;
    size_t off = 0;
    auto alloc = [&](size_t n) { size_t r = off; off += (n + 255) & ~(size_t)255; return r; };
    float* kg      = wsf + alloc(12800000);          // N*D
    float* tmp     = wsf + alloc(12800000);          // sort arena + efeat + split arenas
    ushortT* warena = (ushortT*)(wsf + alloc(196608)); // 12 x 64KB split w[r]
    int*   bsumV   = (int*)(wsf + alloc(2048));
    // ---- contiguous zero block (one memset) ----
    size_t zstart = off;
    int*   heneed  = (int*)(wsf + alloc(DHE2));
    int*   mcnt    = (int*)(wsf + alloc(16));        // [0]=sess, [1]=know
    int*   scnt    = (int*)(wsf + alloc(16));
    float* sdeg_s  = wsf + alloc(4096);
    float* sdeg_k  = wsf + alloc(4096);
    float* sacc_s  = wsf + alloc(524288);
    float* sacc_k  = wsf + alloc(524288);
    size_t zend = off;
    // ---- contiguous 0xFF block (one memset) ----
    size_t fstart = off;
    int*   slot_s  = (int*)(wsf + alloc(100000));
    int*   slot_k  = (int*)(wsf + alloc(100000));
    size_t fend = off;
    int*   pns     = (int*)(wsf + alloc(2 * DP));
    int*   mhe_s   = (int*)(wsf + alloc(MCAP));
    int*   msl_s   = (int*)(wsf + alloc(MCAP));
    int*   mhe_k   = (int*)(wsf + alloc(MCAP));
    int*   msl_k   = (int*)(wsf + alloc(MCAP));
    float* so_s    = wsf + alloc(524288);
    float* so_k    = wsf + alloc(524288);
    float* related = wsf + alloc(1048576);
    float* ctx     = wsf + alloc(262144);
    float* qb      = wsf + alloc(262144);
    float* kb      = wsf + alloc(1048576);
    float* vb      = wsf + alloc(1048576);
    float* obuf    = wsf + alloc(262144);
    float* attrel  = wsf + alloc(262144);
    float* his     = wsf + alloc(8192);
    float* ucat    = wsf + alloc(270336);
    float* userb   = wsf + alloc(8192);
    float* e1      = wsf + alloc(2048);
    float* e2      = wsf + alloc(2112);
    (void)ws_size; (void)in_sizes; (void)n_in; (void)out_size;

    // tmp arena: merged histogram/prefix (rgcn 1.2M + hyper 40K), ssrc, efeat, split arenas
    int*   hist    = (int*)tmp;                 // NALLBINS ints
    int*   soff    = (int*)tmp + 1240000;       // NALLBINS (in-place cursor during bucket)
    int*   ssrc    = (int*)tmp + 2480000;       // 1.0M
    float* efeat   = tmp + 3600000;             // 5.12M
    ushortT* wsplit = (ushortT*)(tmp + 12200000); // 9 x 32768 ushorts
    ushortT* usplit = (ushortT*)(tmp + 12400000); // 16384 ushorts

    const int nbA = (NALLBINS + SCAN_CHUNK - 1) / SCAN_CHUNK;   // 1211

    // ---------------- upfront memsets (3 total)
    hipMemsetAsync(wsf + zstart, 0, (zend - zstart) * 4, stream);
    hipMemsetAsync(wsf + fstart, 0xFF, (fend - fstart) * 4, stream);
    hipMemsetAsync(hist, 0, (size_t)NALLBINS * 4, stream);

    // weight pre-split (independent of everything else)
    k_presplit_all<<<576, 256, 0, stream>>>(root, sess_theta, know_theta, in_proj_w,
                                            out_proj_w, attn_his_a, attn_a, wsplit);

    k_slot_assign2<<<32, 256, 0, stream>>>(sess_rel_idx, know_rel_idx, slot_s, slot_k, scnt);
    k_sdeg_match<<<(DP + 255) / 256, 256, 0, stream>>>(sess_nodes, sess_edges, slot_s,
                                                       sdeg_s, mcnt, mhe_s, msl_s, heneed, 0);
    k_sdeg_match<<<(DP + 255) / 256, 256, 0, stream>>>(know_nodes, know_edges, slot_k,
                                                       sdeg_k, mcnt + 1, mhe_k, msl_k, heneed, DHE);

    // ---------------- merged histogram + single scan + merged bucket
    k_hist_both<<<(DE + 2 * DP + 255) / 256, 256, 0, stream>>>(edge_dst, edge_type, hist,
                                                               sess_edges, know_edges);
    k_scan_pass1<<<nbA, 256, 0, stream>>>(hist, NALLBINS, bsumV);
    k_scan_pass2p<<<1, 256, 0, stream>>>(bsumV, nbA, nullptr);
    k_scan_pass3<<<nbA, 256, 0, stream>>>(hist, NALLBINS, bsumV, soff);
    k_bucket_both<<<(DE + 2 * DP + 255) / 256, 256, 0, stream>>>(
        edge_src, edge_dst, edge_type, soff, ssrc,
        sess_nodes, sess_edges, know_nodes, know_edges, pns);

    k_wcomp_split<<<(DR * DD * DD + 255) / 256, 256, 0, stream>>>(comp, bases, warena);

    // ---------------- fused root + RGCN, stacked-K (one block per 64 dsts, non-atomic kg write)
    int gemmN = (DN + 63) / 64;
    k_rgcn_fk<<<gemmN, 256, 0, stream>>>(emb, wsplit + 0 * 32768, warena, rgcn_bias,
                                         soff, hist, ssrc, kg);

    // ---------------- hypergraph aggregation
    k_hyper_agg<<<(DHE2 * 64 + 255) / 256, 256, 0, stream>>>(kg, pns, soff + NRBINS,
                                                             hist + NRBINS, heneed, efeat);
    k_accmatch2<<<256, 256, 0, stream>>>(efeat, mhe_s, msl_s, mhe_k, msl_k, mcnt, sacc_s, sacc_k);

    k_gemm_ds<<<64, 256, 0, stream>>>(sacc_s, wsplit + 1 * 32768, sess_bias, sdeg_s,
                                      nullptr, nullptr, so_s, 4096);
    k_gemm_ds<<<64, 256, 0, stream>>>(sacc_k, wsplit + 2 * 32768, know_bias, sdeg_k,
                                      nullptr, nullptr, so_k, 4096);
    k_rel_gather2<<<(2 * DB * DLR * 32 + 255) / 256, 256, 0, stream>>>(
        so_s, so_k, slot_s, slot_k, sess_rel_idx, know_rel_idx, related);

    // ---------------- context + MHA (q-GEMM gathers ctx rows from kg and writes ctx)
    k_gemm_ds<<<(DB * DLC + 63) / 64, 256, 0, stream>>>(kg, wsplit + 3 * 32768,
                                                        in_proj_b, nullptr,
                                                        context_idx, ctx, qb, DB * DLC);
    k_gemm_ds<<<(DB * 128 + 63) / 64, 256, 0, stream>>>(related, wsplit + 4 * 32768,
                                                        in_proj_b + DD, nullptr,
                                                        nullptr, nullptr, kb, DB * 128);
    k_gemm_ds<<<(DB * 128 + 63) / 64, 256, 0, stream>>>(related, wsplit + 5 * 32768,
                                                        in_proj_b + 2 * DD, nullptr,
                                                        nullptr, nullptr, vb, DB * 128);
    k_mha<<<DB * DNH, 256, 0, stream>>>(qb, kb, vb, obuf);
    k_gemm_ds<<<(DB * DLC + 63) / 64, 256, 0, stream>>>(obuf, wsplit + 6 * 32768,
                                                        out_proj_b, nullptr,
                                                        nullptr, nullptr, attrel, DB * DLC);

    // ---------------- pooling (GEMM-shaped) + score
    k_tanh_dot_ds<<<(DB * DLC + 63) / 64, 256, 0, stream>>>(attrel, wsplit + 7 * 32768,
                                                            attn_his_b, e1, DB * DLC);
    k_pool_apply<32><<<DB, 128, 0, stream>>>(attrel, e1, his, nullptr);
    k_build_ucat<<<(DB * 33 * 128 + 255) / 256, 256, 0, stream>>>(ctx, his, ucat);
    k_tanh_dot_ds<<<(DB * 33 + 63) / 64, 256, 0, stream>>>(ucat, wsplit + 8 * 32768,
                                                           attn_b, e2, DB * 33);
    k_pool_apply<33><<<DB, 128, 0, stream>>>(ucat, e2, userb, usplit);
    k_score_ds<<<gemmN, 256, 0, stream>>>(kg, usplit, rec_bias, out);
}

// Round 7
// 806.415 us; speedup vs baseline: 2.4619x; 1.1697x over previous
//
#include <hip/hip_runtime.h>
#include <hip/hip_bf16.h>

#define DN 100000     // N entities
#define DD 128        // D
#define DR 12         // R relations
#define DNB 8         // bases
#define DE 1000000    // edges
#define DP 400000     // hyperedge incidences
#define DHE 20000     // hyperedges
#define DHE2 40000    // both sides combined
#define DB 64         // batch
#define DLR 64
#define DLC 32
#define DNH 8
#define DHD 16
#define NRBINS (DR * DN)   // 1.2M
#define NALLBINS (NRBINS + DHE2)
#define SCAN_CHUNK 1024
#define MCAP 65536

typedef unsigned short ushortT;
typedef unsigned int uintT;
typedef __attribute__((ext_vector_type(8))) short s8v;
typedef __attribute__((ext_vector_type(4))) float f4v;

#define APAD 136   // bf16 LDS row stride for 128-K tiles (272B)
#define ASLB 40    // bf16 LDS row stride for 32-K A slabs (80B -> conflict-free b128)
#define BSP 40     // bf16 LDS row stride for 32-K B slabs (80B -> conflict-free b128)

__device__ __forceinline__ ushortT rneb(float v) {
    uintT b = __float_as_uint(v);
    return (ushortT)((b + 0x7FFFu + ((b >> 16) & 1u)) >> 16);
}
__device__ __forceinline__ float b2f(ushortT h) {
    return __uint_as_float(((uintT)h) << 16);
}

__device__ __forceinline__ void split_store8(ushortT* hbase, ushortT* lbase, const float* v)
{
    ushortT h[8], l[8];
    #pragma unroll
    for (int j = 0; j < 8; ++j) {
        h[j] = rneb(v[j]);
        l[j] = rneb(v[j] - b2f(h[j]));
    }
    uint4 hv = make_uint4((uintT)h[0] | ((uintT)h[1] << 16), (uintT)h[2] | ((uintT)h[3] << 16),
                          (uintT)h[4] | ((uintT)h[5] << 16), (uintT)h[6] | ((uintT)h[7] << 16));
    uint4 lv = make_uint4((uintT)l[0] | ((uintT)l[1] << 16), (uintT)l[2] | ((uintT)l[3] << 16),
                          (uintT)l[4] | ((uintT)l[5] << 16), (uintT)l[6] | ((uintT)l[7] << 16));
    *(uint4*)hbase = hv;
    *(uint4*)lbase = lv;
}

// ---------------------------------------------------------------- weight pre-split (blocked fragment layout)
// WB[kc][n][k] ushort, h plane then l plane at +16384.
// 0 root(t0) 1 sess_theta(t0) 2 know_theta(t0) 3 wq(t1) 4 wk(t1) 5 wv(t1)
// 6 out_proj(t1) 7 attn_his_a(t0) 8 attn_a(t0)
__global__ __launch_bounds__(256) void k_presplit_all(
    const float* __restrict__ root, const float* __restrict__ st,
    const float* __restrict__ kt, const float* __restrict__ ipw,
    const float* __restrict__ opw, const float* __restrict__ aha,
    const float* __restrict__ aa, ushortT* __restrict__ outA)
{
    int gid = blockIdx.x * 256 + threadIdx.x;   // 9*16384 exact
    int mat = gid >> 14, e = gid & 16383;
    const float* srcs[9] = {root, st, kt, ipw, ipw + 16384, ipw + 32768, opw, aha, aa};
    const float* W = srcs[mat];
    bool t1 = (mat >= 3 && mat <= 6);
    int k = e & 31, n = (e >> 5) & 127, kc = e >> 12;
    float f = t1 ? W[(size_t)n * 128 + kc * 32 + k] : W[(size_t)(kc * 32 + k) * 128 + n];
    ushortT h = rneb(f);
    outA[(size_t)mat * 32768 + e] = h;
    outA[(size_t)mat * 32768 + 16384 + e] = rneb(f - b2f(h));
}

// w[r] = comp[r]·bases, split directly into blocked layout (64KB per r: h 32KB, l 32KB)
__global__ void k_wcomp_split(const float* __restrict__ comp, const float* __restrict__ bases,
                              ushortT* __restrict__ warena)
{
    int i = blockIdx.x * blockDim.x + threadIdx.x;
    if (i >= DR * DD * DD) return;
    int r = i / (DD * DD), io = i % (DD * DD);
    float s = 0.f;
    #pragma unroll
    for (int b = 0; b < DNB; ++b) s += comp[r * DNB + b] * bases[(size_t)b * DD * DD + io];
    int irow = io >> 7, o = io & 127;          // irow = k-dim
    int kc = irow >> 5, k = irow & 31;
    size_t dst = (size_t)r * 32768 + (size_t)kc * 4096 + o * 32 + k;
    ushortT h = rneb(s);
    warena[dst] = h;
    warena[dst + 16384] = rneb(s - b2f(h));
}

// ---------------------------------------------------------------- MFMA GEMM, B copy-staged per kc from pre-split global
__global__ __launch_bounds__(256) void k_gemm_ds(
    const float* __restrict__ A, const ushortT* __restrict__ Wb,
    const float* __restrict__ bias, const float* __restrict__ rs,
    const int* __restrict__ gidx, float* __restrict__ gout,
    float* __restrict__ C, int M)
{
    __shared__ __align__(16) ushortT Ah[64 * APAD], Al[64 * APAD];
    __shared__ __align__(16) ushortT Bs[8192];
    int tid = threadIdx.x;
    int row0 = blockIdx.x * 64;
    {
        int row = tid >> 2, c0 = (tid & 3) * 32;
        int gr = row0 + row;
        int arow = gr;
        if (gidx && gr < M) arow = gidx[gr];
        const float* ar = A + (size_t)arow * 128 + c0;
        float sc = 1.0f;
        if (rs && gr < M) { float d = rs[gr]; sc = (d > 0.f) ? 1.0f / d : 0.f; }
        #pragma unroll
        for (int g = 0; g < 4; ++g) {
            float v[8] = {};
            if (gr < M) {
                float4 u0 = *(const float4*)(ar + g * 8);
                float4 u1 = *(const float4*)(ar + g * 8 + 4);
                v[0]=u0.x*sc; v[1]=u0.y*sc; v[2]=u0.z*sc; v[3]=u0.w*sc;
                v[4]=u1.x*sc; v[5]=u1.y*sc; v[6]=u1.z*sc; v[7]=u1.w*sc;
                if (gout) {
                    *(float4*)(gout + (size_t)gr * 128 + c0 + g * 8)     = u0;
                    *(float4*)(gout + (size_t)gr * 128 + c0 + g * 8 + 4) = u1;
                }
            }
            split_store8(&Ah[row * APAD + c0 + g * 8], &Al[row * APAD + c0 + g * 8], v);
        }
    }
    f4v acc[8] = {};
    int w = tid >> 6, lane = tid & 63, m = lane & 15, quad = lane >> 4;
    for (int kc = 0; kc < 4; ++kc) {
        __syncthreads();
        {
            const ushortT* gh = Wb + kc * 4096;
            const ushortT* gl = Wb + 16384 + kc * 4096;
            *(s8v*)&Bs[tid * 8]        = *(const s8v*)&gh[tid * 8];
            *(s8v*)&Bs[2048 + tid * 8] = *(const s8v*)&gh[2048 + tid * 8];
            *(s8v*)&Bs[4096 + tid * 8] = *(const s8v*)&gl[tid * 8];
            *(s8v*)&Bs[6144 + tid * 8] = *(const s8v*)&gl[2048 + tid * 8];
        }
        __syncthreads();
        s8v ah = *(const s8v*)&Ah[(w * 16 + m) * APAD + kc * 32 + quad * 8];
        s8v al = *(const s8v*)&Al[(w * 16 + m) * APAD + kc * 32 + quad * 8];
        #pragma unroll
        for (int nt = 0; nt < 8; ++nt) {
            int boff = (nt * 16 + m) * 32 + quad * 8;
            s8v bh = *(const s8v*)&Bs[boff];
            s8v bl = *(const s8v*)&Bs[4096 + boff];
            acc[nt] = __builtin_amdgcn_mfma_f32_16x16x32_bf16(ah, bh, acc[nt], 0, 0, 0);
            acc[nt] = __builtin_amdgcn_mfma_f32_16x16x32_bf16(al, bh, acc[nt], 0, 0, 0);
            acc[nt] = __builtin_amdgcn_mfma_f32_16x16x32_bf16(ah, bl, acc[nt], 0, 0, 0);
        }
    }
    float bv[8];
    #pragma unroll
    for (int nt = 0; nt < 8; ++nt) bv[nt] = bias ? bias[nt * 16 + m] : 0.f;
    #pragma unroll
    for (int rr = 0; rr < 4; ++rr) {
        int gr = row0 + w * 16 + quad * 4 + rr;
        if (gr < M) {
            #pragma unroll
            for (int nt = 0; nt < 8; ++nt)
                C[(size_t)gr * 128 + nt * 16 + m] = acc[nt][rr] + bv[nt];
        }
    }
}

// ---------------------------------------------------------------- fused e[row] = tanh(A@W)[row,:] . bvec
__global__ __launch_bounds__(256) void k_tanh_dot_ds(
    const float* __restrict__ A, const ushortT* __restrict__ Wb,
    const float* __restrict__ bvec, float* __restrict__ e, int M)
{
    __shared__ __align__(16) ushortT Ah[64 * APAD], Al[64 * APAD];
    __shared__ __align__(16) ushortT Bs[8192];
    int tid = threadIdx.x;
    int row0 = blockIdx.x * 64;
    {
        int row = tid >> 2, c0 = (tid & 3) * 32;
        int gr = row0 + row;
        const float* ar = A + (size_t)gr * 128 + c0;
        #pragma unroll
        for (int g = 0; g < 4; ++g) {
            float v[8] = {};
            if (gr < M) {
                float4 u0 = *(const float4*)(ar + g * 8);
                float4 u1 = *(const float4*)(ar + g * 8 + 4);
                v[0]=u0.x; v[1]=u0.y; v[2]=u0.z; v[3]=u0.w;
                v[4]=u1.x; v[5]=u1.y; v[6]=u1.z; v[7]=u1.w;
            }
            split_store8(&Ah[row * APAD + c0 + g * 8], &Al[row * APAD + c0 + g * 8], v);
        }
    }
    f4v acc[8] = {};
    int w = tid >> 6, lane = tid & 63, m = lane & 15, quad = lane >> 4;
    for (int kc = 0; kc < 4; ++kc) {
        __syncthreads();
        {
            const ushortT* gh = Wb + kc * 4096;
            const ushortT* gl = Wb + 16384 + kc * 4096;
            *(s8v*)&Bs[tid * 8]        = *(const s8v*)&gh[tid * 8];
            *(s8v*)&Bs[2048 + tid * 8] = *(const s8v*)&gh[2048 + tid * 8];
            *(s8v*)&Bs[4096 + tid * 8] = *(const s8v*)&gl[tid * 8];
            *(s8v*)&Bs[6144 + tid * 8] = *(const s8v*)&gl[2048 + tid * 8];
        }
        __syncthreads();
        s8v ah = *(const s8v*)&Ah[(w * 16 + m) * APAD + kc * 32 + quad * 8];
        s8v al = *(const s8v*)&Al[(w * 16 + m) * APAD + kc * 32 + quad * 8];
        #pragma unroll
        for (int nt = 0; nt < 8; ++nt) {
            int boff = (nt * 16 + m) * 32 + quad * 8;
            s8v bh = *(const s8v*)&Bs[boff];
            s8v bl = *(const s8v*)&Bs[4096 + boff];
            acc[nt] = __builtin_amdgcn_mfma_f32_16x16x32_bf16(ah, bh, acc[nt], 0, 0, 0);
            acc[nt] = __builtin_amdgcn_mfma_f32_16x16x32_bf16(al, bh, acc[nt], 0, 0, 0);
            acc[nt] = __builtin_amdgcn_mfma_f32_16x16x32_bf16(ah, bl, acc[nt], 0, 0, 0);
        }
    }
    float bv[8];
    #pragma unroll
    for (int nt = 0; nt < 8; ++nt) bv[nt] = bvec[nt * 16 + m];
    #pragma unroll
    for (int rr = 0; rr < 4; ++rr) {
        float p = 0.f;
        #pragma unroll
        for (int nt = 0; nt < 8; ++nt) p += tanhf(acc[nt][rr]) * bv[nt];
        #pragma unroll
        for (int o = 1; o < 16; o <<= 1) p += __shfl_xor(p, o);
        int gr = row0 + w * 16 + quad * 4 + rr;
        if (m == 0 && gr < M) e[gr] = p;
    }
}

// ---------------------------------------------------------------- softmax(e) weighted sum of h rows (+ optional user split)
template <int L>
__global__ __launch_bounds__(128) void k_pool_apply(const float* __restrict__ h,
                                                    const float* __restrict__ e,
                                                    float* __restrict__ out,
                                                    ushortT* __restrict__ us)
{
    __shared__ float es[L];
    int b = blockIdx.x, tid = threadIdx.x;
    if (tid < L) es[tid] = e[b * L + tid];
    __syncthreads();
    float mx = -1e30f;
    #pragma unroll
    for (int l = 0; l < L; ++l) mx = fmaxf(mx, es[l]);
    float wgt[L];
    float sum = 0.f;
    #pragma unroll
    for (int l = 0; l < L; ++l) { wgt[l] = __expf(es[l] - mx); sum += wgt[l]; }
    float inv = 1.0f / sum;
    float o = 0.f;
    #pragma unroll
    for (int l = 0; l < L; ++l) o += wgt[l] * h[((size_t)b * L + l) * 128 + tid];
    float val = o * inv;
    out[(size_t)b * 128 + tid] = val;
    if (us) {
        ushortT hh = rneb(val);
        ushortT ll = rneb(val - b2f(hh));
        int e_ = ((tid >> 5) * 2048) + b * 32 + (tid & 31);
        us[e_] = hh;
        us[8192 + e_] = ll;
    }
}

__global__ void k_build_ucat(const float* __restrict__ ctx, const float* __restrict__ his,
                             float* ucat)
{
    int i = blockIdx.x * blockDim.x + threadIdx.x;
    if (i >= DB * 33 * 128) return;
    int d = i & 127, l = (i >> 7) % 33, b = i / (33 * 128);
    ucat[i] = (l < 32) ? ctx[((size_t)b * 32 + l) * 128 + d] : his[(size_t)b * 128 + d];
}

// ---------------------------------------------------------------- fused root + RGCN, stacked-K formulation (v2).
// One block owns 64 dsts. kg[dst] = [x[dst] | mean_0 | ... | mean_11] @ [root; w_0; ...; w_11] + bias.
// Per relation: gather FULL 32-float thread footprint once (8 indep loads/edge), then 4 kci MFMA
// slabs consume a+kci*8 (kci fully unrolled -> static reg indexing). B slab rows padded to 40
// ushorts (80B stride) -> conflict-free ds_read_b128. One non-atomic 512B write per dst.
__global__ __launch_bounds__(256) void k_rgcn_fk(
    const float* __restrict__ x, const ushortT* __restrict__ rootsplit,
    const ushortT* __restrict__ warena, const float* __restrict__ bias,
    const int* __restrict__ soff, const int* __restrict__ hist,
    const int* __restrict__ ssrc, float* __restrict__ kg)
{
    __shared__ __align__(16) ushortT Ah[64 * ASLB], Al[64 * ASLB];
    __shared__ __align__(16) ushortT Bs[2 * 128 * BSP];   // h plane, l plane at +128*BSP
    int tid = threadIdx.x;
    int dst0 = blockIdx.x * 64;
    int nrow = min(64, DN - dst0);
    int w = tid >> 6, lane = tid & 63, m = lane & 15, quad = lane >> 4;
    int row = tid >> 2, ci = (tid & 3) * 8;
    int brow = tid & 127, bpl = tid >> 7;   // B staging: row, plane(h/l)
    f4v acc[8] = {};

    for (int p = 0; p < 13; ++p) {
        float a[32];
        if (row < nrow) {
            if (p == 0) {
                const float* ar = x + (size_t)(dst0 + row) * 128 + ci;
                #pragma unroll
                for (int k = 0; k < 4; ++k) {
                    float4 u0 = *(const float4*)(ar + k * 32);
                    float4 u1 = *(const float4*)(ar + k * 32 + 4);
                    a[k*8+0]=u0.x; a[k*8+1]=u0.y; a[k*8+2]=u0.z; a[k*8+3]=u0.w;
                    a[k*8+4]=u1.x; a[k*8+5]=u1.y; a[k*8+6]=u1.z; a[k*8+7]=u1.w;
                }
            } else {
                #pragma unroll
                for (int j = 0; j < 32; ++j) a[j] = 0.f;
                int key = (dst0 + row) * DR + (p - 1);
                int len = hist[key];
                int st = soff[key] - len;   // soff is in-place inclusive end after bucketing
                for (int i = 0; i < len; ++i) {
                    const float* xr = x + (size_t)ssrc[st + i] * 128 + ci;
                    #pragma unroll
                    for (int k = 0; k < 4; ++k) {
                        float4 u0 = *(const float4*)(xr + k * 32);
                        float4 u1 = *(const float4*)(xr + k * 32 + 4);
                        a[k*8+0]+=u0.x; a[k*8+1]+=u0.y; a[k*8+2]+=u0.z; a[k*8+3]+=u0.w;
                        a[k*8+4]+=u1.x; a[k*8+5]+=u1.y; a[k*8+6]+=u1.z; a[k*8+7]+=u1.w;
                    }
                }
                float inv = (len > 0) ? 1.0f / (float)len : 0.f;
                #pragma unroll
                for (int j = 0; j < 32; ++j) a[j] *= inv;
            }
        } else {
            #pragma unroll
            for (int j = 0; j < 32; ++j) a[j] = 0.f;
        }
        const ushortT* Wb = (p == 0) ? rootsplit : warena + (size_t)(p - 1) * 32768;
        #pragma unroll
        for (int kci = 0; kci < 4; ++kci) {
            __syncthreads();   // prior slab's LDS reads complete
            split_store8(&Ah[row * ASLB + ci], &Al[row * ASLB + ci], a + kci * 8);
            {   // stage B slab [128][32] -> padded rows of BSP ushorts; thread copies one row-plane
                const ushortT* src = Wb + bpl * 16384 + kci * 4096 + brow * 32;
                ushortT* dstp = &Bs[bpl * (128 * BSP) + brow * BSP];
                *(s8v*)&dstp[0]  = *(const s8v*)&src[0];
                *(s8v*)&dstp[8]  = *(const s8v*)&src[8];
                *(s8v*)&dstp[16] = *(const s8v*)&src[16];
                *(s8v*)&dstp[24] = *(const s8v*)&src[24];
            }
            __syncthreads();
            s8v ah = *(const s8v*)&Ah[(w * 16 + m) * ASLB + quad * 8];
            s8v al = *(const s8v*)&Al[(w * 16 + m) * ASLB + quad * 8];
            #pragma unroll
            for (int nt = 0; nt < 8; ++nt) {
                int boff = (nt * 16 + m) * BSP + quad * 8;
                s8v bh = *(const s8v*)&Bs[boff];
                s8v bl2 = *(const s8v*)&Bs[128 * BSP + boff];
                acc[nt] = __builtin_amdgcn_mfma_f32_16x16x32_bf16(ah, bh, acc[nt], 0, 0, 0);
                acc[nt] = __builtin_amdgcn_mfma_f32_16x16x32_bf16(al, bh, acc[nt], 0, 0, 0);
                acc[nt] = __builtin_amdgcn_mfma_f32_16x16x32_bf16(ah, bl2, acc[nt], 0, 0, 0);
            }
        }
    }
    float bv[8];
    #pragma unroll
    for (int nt = 0; nt < 8; ++nt) bv[nt] = bias[nt * 16 + m];
    #pragma unroll
    for (int rr = 0; rr < 4; ++rr) {
        int gr = dst0 + w * 16 + quad * 4 + rr;
        if (gr < DN) {
            #pragma unroll
            for (int nt = 0; nt < 8; ++nt)
                kg[(size_t)gr * 128 + nt * 16 + m] = acc[nt][rr] + bv[nt];
        }
    }
}

// ---------------------------------------------------------------- scoring (MFMA, B copy-staged from pre-split user)
__global__ __launch_bounds__(256) void k_score_ds(
    const float* __restrict__ kg, const ushortT* __restrict__ Ub,
    const float* __restrict__ rb, float* __restrict__ out)
{
    __shared__ __align__(16) ushortT Ah[64 * APAD], Al[64 * APAD];
    __shared__ __align__(16) ushortT Bs[4096];
    int tid = threadIdx.x;
    int n0 = blockIdx.x * 64;
    {
        int row = tid >> 2, c0 = (tid & 3) * 32;
        int gr = n0 + row;
        const float* ar = kg + (size_t)gr * 128 + c0;
        #pragma unroll
        for (int g = 0; g < 4; ++g) {
            float v[8] = {};
            if (gr < DN) {
                float4 u0 = *(const float4*)(ar + g * 8);
                float4 u1 = *(const float4*)(ar + g * 8 + 4);
                v[0]=u0.x; v[1]=u0.y; v[2]=u0.z; v[3]=u0.w;
                v[4]=u1.x; v[5]=u1.y; v[6]=u1.z; v[7]=u1.w;
            }
            split_store8(&Ah[row * APAD + c0 + g * 8], &Al[row * APAD + c0 + g * 8], v);
        }
    }
    f4v acc[4] = {};
    int w = tid >> 6, lane = tid & 63, m = lane & 15, quad = lane >> 4;
    for (int kc = 0; kc < 4; ++kc) {
        __syncthreads();
        {
            const ushortT* gh = Ub + kc * 2048;
            const ushortT* gl = Ub + 8192 + kc * 2048;
            *(s8v*)&Bs[tid * 8]        = *(const s8v*)&gh[tid * 8];
            *(s8v*)&Bs[2048 + tid * 8] = *(const s8v*)&gl[tid * 8];
        }
        __syncthreads();
        s8v ah = *(const s8v*)&Ah[(w * 16 + m) * APAD + kc * 32 + quad * 8];
        s8v al = *(const s8v*)&Al[(w * 16 + m) * APAD + kc * 32 + quad * 8];
        #pragma unroll
        for (int nt = 0; nt < 4; ++nt) {
            int boff = (nt * 16 + m) * 32 + quad * 8;
            s8v bh = *(const s8v*)&Bs[boff];
            s8v bl = *(const s8v*)&Bs[2048 + boff];
            acc[nt] = __builtin_amdgcn_mfma_f32_16x16x32_bf16(ah, bh, acc[nt], 0, 0, 0);
            acc[nt] = __builtin_amdgcn_mfma_f32_16x16x32_bf16(al, bh, acc[nt], 0, 0, 0);
            acc[nt] = __builtin_amdgcn_mfma_f32_16x16x32_bf16(ah, bl, acc[nt], 0, 0, 0);
        }
    }
    int n = n0 + w * 16 + quad * 4;
    if (n < DN) {
        float4 rbv = *(const float4*)&rb[n];
        #pragma unroll
        for (int nt = 0; nt < 4; ++nt) {
            int b = nt * 16 + m;
            float4 o = make_float4(acc[nt][0] + rbv.x, acc[nt][1] + rbv.y,
                                   acc[nt][2] + rbv.z, acc[nt][3] + rbv.w);
            *(float4*)&out[(size_t)b * DN + n] = o;
        }
    }
}

// ---------------------------------------------------------------- scans (single merged array: rgcn bins + hyper bins)
__global__ void k_scan_pass1(const int* __restrict__ in, int n, int* __restrict__ bsum)
{
    __shared__ int red[256];
    int b = blockIdx.x, t = threadIdx.x;
    int i0 = b * SCAN_CHUNK + t * 4;
    int s = 0;
    #pragma unroll
    for (int j = 0; j < 4; ++j) {
        int i = i0 + j;
        if (i < n) s += in[i];
    }
    red[t] = s;
    __syncthreads();
    for (int o = 128; o > 0; o >>= 1) {
        if (t < o) red[t] += red[t + o];
        __syncthreads();
    }
    if (t == 0) bsum[b] = red[0];
}

__global__ __launch_bounds__(256) void k_scan_pass2p(int* bsum, int nb, int* total)
{
    __shared__ int lds[256];
    __shared__ int carry;
    int t = threadIdx.x;
    if (t == 0) carry = 0;
    __syncthreads();
    for (int c0 = 0; c0 < nb; c0 += 256) {
        int i = c0 + t;
        int v = (i < nb) ? bsum[i] : 0;
        lds[t] = v;
        __syncthreads();
        for (int o = 1; o < 256; o <<= 1) {
            int add = (t >= o) ? lds[t - o] : 0;
            __syncthreads();
            lds[t] += add;
            __syncthreads();
        }
        int myc = carry;
        if (i < nb) bsum[i] = lds[t] - v + myc;
        int tot = lds[255];
        __syncthreads();
        if (t == 0) carry = myc + tot;
        __syncthreads();
    }
    if (total && t == 0) *total = carry;
}

__global__ void k_scan_pass3(const int* __restrict__ in, int n, const int* __restrict__ bsum,
                             int* __restrict__ out)
{
    __shared__ int lds[256];
    int b = blockIdx.x, t = threadIdx.x;
    int i0 = b * SCAN_CHUNK + t * 4;
    int v[4]; int s = 0;
    #pragma unroll
    for (int j = 0; j < 4; ++j) {
        int i = i0 + j;
        int x = 0;
        if (i < n) x = in[i];
        v[j] = x; s += x;
    }
    lds[t] = s;
    __syncthreads();
    for (int o = 1; o < 256; o <<= 1) {
        int add = (t >= o) ? lds[t - o] : 0;
        __syncthreads();
        lds[t] += add;
        __syncthreads();
    }
    int run = lds[t] - s + bsum[b];
    #pragma unroll
    for (int j = 0; j < 4; ++j) {
        int i = i0 + j;
        if (i < n) { out[i] = run; run += v[j]; }
    }
}

// ---------------------------------------------------------------- merged histogram (RGCN key = dst*DR + et; hyper at +NRBINS)
__global__ void k_hist_both(const int* __restrict__ dst, const int* __restrict__ et,
                            int* __restrict__ hist,
                            const int* __restrict__ se, const int* __restrict__ ke)
{
    int i = blockIdx.x * blockDim.x + threadIdx.x;
    if (i < DE) {
        atomicAdd(&hist[dst[i] * DR + et[i]], 1);
    } else {
        int j = i - DE;
        if (j < DP) atomicAdd(&hist[NRBINS + se[j]], 1);
        else if (j < 2 * DP) atomicAdd(&hist[NRBINS + DHE + ke[j - DP]], 1);
    }
}

// merged bucket scatter (in-place cursor). Hyper positions are offset by DE (concat prefix) -> pns[pos-DE].
__global__ void k_bucket_both(const int* __restrict__ src, const int* __restrict__ dst,
                              const int* __restrict__ et, int* __restrict__ soff,
                              int* __restrict__ ssrc,
                              const int* __restrict__ sn, const int* __restrict__ se,
                              const int* __restrict__ kn, const int* __restrict__ ke,
                              int* __restrict__ pns)
{
    int i = blockIdx.x * blockDim.x + threadIdx.x;
    if (i < DE) {
        int key = dst[i] * DR + et[i];
        int pos = atomicAdd(&soff[key], 1);
        ssrc[pos] = src[i];
    } else {
        int j = i - DE;
        if (j >= 2 * DP) return;
        int e, node;
        if (j < DP) { e = se[j]; node = sn[j]; }
        else { e = DHE + ke[j - DP]; node = kn[j - DP]; }
        int pos = atomicAdd(&soff[NRBINS + e], 1);
        pns[pos - DE] = node;
    }
}

// one wave per NEEDED hyperedge; st from in-place cursor (minus DE concat offset)
__global__ void k_hyper_agg(const float* __restrict__ xsrc, const int* __restrict__ pns,
                            const int* __restrict__ hoff, const int* __restrict__ hcnt,
                            const int* __restrict__ heneed, float* __restrict__ efeat)
{
    int lane = threadIdx.x & 63;
    int he = (blockIdx.x * blockDim.x + threadIdx.x) >> 6;
    if (he >= DHE2) return;
    if (!heneed[he]) return;
    int len = hcnt[he];
    int st = hoff[he] - len - DE;
    int half = lane >> 5;
    int c16 = (lane & 31) * 4;
    float4 acc = make_float4(0.f, 0.f, 0.f, 0.f);
    int c = 0;
    for (; c + 4 <= len; c += 4) {
        int n0 = pns[st + c + half];
        int n1 = pns[st + c + 2 + half];
        float4 v0 = *(const float4*)&xsrc[(size_t)n0 * 128 + c16];
        float4 v1 = *(const float4*)&xsrc[(size_t)n1 * 128 + c16];
        acc.x += v0.x + v1.x; acc.y += v0.y + v1.y;
        acc.z += v0.z + v1.z; acc.w += v0.w + v1.w;
    }
    for (; c < len; c += 2) {
        int idx = c + half;
        if (idx < len) {
            int n = pns[st + idx];
            float4 v = *(const float4*)&xsrc[(size_t)n * 128 + c16];
            acc.x += v.x; acc.y += v.y; acc.z += v.z; acc.w += v.w;
        }
    }
    acc.x += __shfl_xor(acc.x, 32);
    acc.y += __shfl_xor(acc.y, 32);
    acc.z += __shfl_xor(acc.z, 32);
    acc.w += __shfl_xor(acc.w, 32);
    if (half == 0) {
        float inv = (len > 0) ? 1.0f / (float)len : 0.f;
        float4 o = make_float4(acc.x * inv, acc.y * inv, acc.z * inv, acc.w * inv);
        *(float4*)&efeat[(size_t)he * 128 + c16] = o;
    }
}

__global__ void k_slot_assign2(const int* __restrict__ sidx, const int* __restrict__ kidx,
                               int* slot_s, int* slot_k, int* scnt)
{
    int i = blockIdx.x * blockDim.x + threadIdx.x;
    if (i < DB * DLR) {
        int node = sidx[i];
        if (atomicCAS(&slot_s[node], -1, -2) == -1) slot_s[node] = atomicAdd(&scnt[0], 1);
    } else if (i < 2 * DB * DLR) {
        int node = kidx[i - DB * DLR];
        if (atomicCAS(&slot_k[node], -1, -2) == -1) slot_k[node] = atomicAdd(&scnt[1], 1);
    }
}

// fused sdeg + match + need-flag, block-aggregated compaction
__global__ __launch_bounds__(256) void k_sdeg_match(
    const int* __restrict__ nodes, const int* __restrict__ he, const int* __restrict__ slot,
    float* sdeg, int* mcnt, int* mhe, int* msl, int* heneed, int heBase)
{
    __shared__ int lcnt, lbase;
    if (threadIdx.x == 0) lcnt = 0;
    __syncthreads();
    int i = blockIdx.x * 256 + threadIdx.x;
    int s = -1, lidx = 0, h = 0;
    if (i < DP) {
        s = slot[nodes[i]];
        if (s >= 0) {
            h = heBase + he[i];
            heneed[h] = 1;
            atomicAdd(&sdeg[s], 1.0f);
            lidx = atomicAdd(&lcnt, 1);
        }
    }
    __syncthreads();
    if (threadIdx.x == 0) lbase = (lcnt > 0) ? atomicAdd(mcnt, lcnt) : 0;
    __syncthreads();
    if (s >= 0) {
        int idx = lbase + lidx;
        if (idx < MCAP) { mhe[idx] = h; msl[idx] = s; }
    }
}

// both sides in one launch
__global__ void k_accmatch2(const float* __restrict__ efeat,
                            const int* __restrict__ mhe_s, const int* __restrict__ msl_s,
                            const int* __restrict__ mhe_k, const int* __restrict__ msl_k,
                            const int* __restrict__ mcnt,
                            float* sacc_s, float* sacc_k)
{
    int lane = threadIdx.x & 63;
    int w = (blockIdx.x * blockDim.x + threadIdx.x) >> 6;
    int nw = (gridDim.x * blockDim.x) >> 6;
    int Ms = min(mcnt[0], MCAP), Mk = min(mcnt[1], MCAP);
    for (int i = w; i < Ms + Mk; i += nw) {
        bool sess = i < Ms;
        int he = sess ? mhe_s[i] : mhe_k[i - Ms];
        int sl = sess ? msl_s[i] : msl_k[i - Ms];
        float* sacc = sess ? sacc_s : sacc_k;
        float2 v = *(const float2*)&efeat[(size_t)he * 128 + lane * 2];
        atomicAdd(&sacc[(size_t)sl * 128 + lane * 2],     v.x);
        atomicAdd(&sacc[(size_t)sl * 128 + lane * 2 + 1], v.y);
    }
}

// both sides in one launch
__global__ void k_rel_gather2(const float* __restrict__ so_s, const float* __restrict__ so_k,
                              const int* __restrict__ slot_s, const int* __restrict__ slot_k,
                              const int* __restrict__ ridx_s, const int* __restrict__ ridx_k,
                              float* __restrict__ related)
{
    int gid = blockIdx.x * blockDim.x + threadIdx.x;
    int i = gid >> 5, c = gid & 31;
    if (i >= 2 * DB * DLR) return;
    bool sess = i < DB * DLR;
    int ii = sess ? i : i - DB * DLR;
    int s = sess ? slot_s[ridx_s[ii]] : slot_k[ridx_k[ii]];
    const float* so = sess ? so_s : so_k;
    int b = ii / DLR, l = ii % DLR;
    int colOff = sess ? 0 : 64;
    ((float4*)&related[((size_t)b * 128 + colOff + l) * 128])[c] =
        ((const float4*)&so[(size_t)s * 128])[c];
}

// ---------------------------------------------------------------- MHA: one block per (b,h)
__global__ __launch_bounds__(256) void k_mha(const float* __restrict__ qb,
                                             const float* __restrict__ kb,
                                             const float* __restrict__ vb,
                                             float* __restrict__ ob)
{
    int b = blockIdx.x >> 3, h = blockIdx.x & 7;
    __shared__ float Ks[128][16], Vs[128][16], Qs[32][16];
    int tid = threadIdx.x;
    for (int i = tid; i < 128 * 16; i += 256) {
        int j = i >> 4, d = i & 15;
        Ks[j][d] = kb[((size_t)b * 128 + j) * 128 + h * 16 + d];
        Vs[j][d] = vb[((size_t)b * 128 + j) * 128 + h * 16 + d];
    }
    for (int i = tid; i < 32 * 16; i += 256) {
        int q = i >> 4, d = i & 15;
        Qs[q][d] = qb[((size_t)b * 32 + q) * 128 + h * 16 + d] * 0.25f;
    }
    __syncthreads();
    int q = tid >> 3;
    int jg = tid & 7;
    float lg[16];
    float m = -1e30f;
    #pragma unroll
    for (int jj = 0; jj < 16; ++jj) {
        int j = jg * 16 + jj;
        float s = 0.f;
        #pragma unroll
        for (int d = 0; d < 16; ++d) s += Qs[q][d] * Ks[j][d];
        lg[jj] = s;
        m = fmaxf(m, s);
    }
    #pragma unroll
    for (int o = 1; o < 8; o <<= 1) m = fmaxf(m, __shfl_xor(m, o));
    float sum = 0.f;
    float acc[16] = {};
    #pragma unroll
    for (int jj = 0; jj < 16; ++jj) {
        float p = __expf(lg[jj] - m);
        sum += p;
        int j = jg * 16 + jj;
        #pragma unroll
        for (int d = 0; d < 16; ++d) acc[d] += p * Vs[j][d];
    }
    #pragma unroll
    for (int o = 1; o < 8; o <<= 1) {
        sum += __shfl_xor(sum, o);
        #pragma unroll
        for (int d = 0; d < 16; ++d) acc[d] += __shfl_xor(acc[d], o);
    }
    if (jg == 0) {
        float inv = 1.0f / sum;
        #pragma unroll
        for (int d = 0; d < 16; ++d)
            ob[((size_t)b * 32 + q) * 128 + h * 16 + d] = acc[d] * inv;
    }
}

// ---------------------------------------------------------------- launch
extern "C" void kernel_launch(void* const* d_in, const int* in_sizes, int n_in,
                              void* d_out, int out_size, void* d_ws, size_t ws_size,
                              hipStream_t stream)
{
    const float* emb        = (const float*)d_in[0];
    const float* bases      = (const float*)d_in[1];
    const float* comp       = (const float*)d_in[2];
    const float* root       = (const float*)d_in[3];
    const float* rgcn_bias  = (const float*)d_in[4];
    const float* sess_theta = (const float*)d_in[5];
    const float* sess_bias  = (const float*)d_in[6];
    const float* know_theta = (const float*)d_in[7];
    const float* know_bias  = (const float*)d_in[8];
    const float* in_proj_w  = (const float*)d_in[9];
    const float* in_proj_b  = (const float*)d_in[10];
    const float* out_proj_w = (const float*)d_in[11];
    const float* out_proj_b = (const float*)d_in[12];
    const float* attn_his_a = (const float*)d_in[13];
    const float* attn_his_b = (const float*)d_in[14];
    const float* attn_a     = (const float*)d_in[15];
    const float* attn_b     = (const float*)d_in[16];
    const float* rec_bias   = (const float*)d_in[17];
    const int* edge_src     = (const int*)d_in[18];
    const int* edge_dst     = (const int*)d_in[19];
    const int* edge_type    = (const int*)d_in[20];
    const int* sess_nodes   = (const int*)d_in[21];
    const int* sess_edges   = (const int*)d_in[22];
    const int* know_nodes   = (const int*)d_in[23];
    const int* know_edges   = (const int*)d_in[24];
    const int* sess_rel_idx = (const int*)d_in[25];
    const int* know_rel_idx = (const int*)d_in[26];
    const int* context_idx  = (const int*)d_in[27];
    float* out = (float*)d_out;

    float* wsf = (float*)d_ws;
    size_t off = 0;
    auto alloc = [&](size_t n) { size_t r = off; off += (n + 255) & ~(size_t)255; return r; };
    float* kg      = wsf + alloc(12800000);          // N*D
    float* tmp     = wsf + alloc(12800000);          // sort arena + efeat + split arenas
    ushortT* warena = (ushortT*)(wsf + alloc(196608)); // 12 x 64KB split w[r]
    int*   bsumV   = (int*)(wsf + alloc(2048));
    // ---- contiguous zero block (one memset) ----
    size_t zstart = off;
    int*   heneed  = (int*)(wsf + alloc(DHE2));
    int*   mcnt    = (int*)(wsf + alloc(16));        // [0]=sess, [1]=know
    int*   scnt    = (int*)(wsf + alloc(16));
    float* sdeg_s  = wsf + alloc(4096);
    float* sdeg_k  = wsf + alloc(4096);
    float* sacc_s  = wsf + alloc(524288);
    float* sacc_k  = wsf + alloc(524288);
    size_t zend = off;
    // ---- contiguous 0xFF block (one memset) ----
    size_t fstart = off;
    int*   slot_s  = (int*)(wsf + alloc(100000));
    int*   slot_k  = (int*)(wsf + alloc(100000));
    size_t fend = off;
    int*   pns     = (int*)(wsf + alloc(2 * DP));
    int*   mhe_s   = (int*)(wsf + alloc(MCAP));
    int*   msl_s   = (int*)(wsf + alloc(MCAP));
    int*   mhe_k   = (int*)(wsf + alloc(MCAP));
    int*   msl_k   = (int*)(wsf + alloc(MCAP));
    float* so_s    = wsf + alloc(524288);
    float* so_k    = wsf + alloc(524288);
    float* related = wsf + alloc(1048576);
    float* ctx     = wsf + alloc(262144);
    float* qb      = wsf + alloc(262144);
    float* kb      = wsf + alloc(1048576);
    float* vb      = wsf + alloc(1048576);
    float* obuf    = wsf + alloc(262144);
    float* attrel  = wsf + alloc(262144);
    float* his     = wsf + alloc(8192);
    float* ucat    = wsf + alloc(270336);
    float* userb   = wsf + alloc(8192);
    float* e1      = wsf + alloc(2048);
    float* e2      = wsf + alloc(2112);
    (void)ws_size; (void)in_sizes; (void)n_in; (void)out_size;

    // tmp arena: merged histogram/prefix (rgcn 1.2M + hyper 40K), ssrc, efeat, split arenas
    int*   hist    = (int*)tmp;                 // NALLBINS ints
    int*   soff    = (int*)tmp + 1240000;       // NALLBINS (in-place cursor during bucket)
    int*   ssrc    = (int*)tmp + 2480000;       // 1.0M
    float* efeat   = tmp + 3600000;             // 5.12M
    ushortT* wsplit = (ushortT*)(tmp + 12200000); // 9 x 32768 ushorts
    ushortT* usplit = (ushortT*)(tmp + 12400000); // 16384 ushorts

    const int nbA = (NALLBINS + SCAN_CHUNK - 1) / SCAN_CHUNK;   // 1211

    // ---------------- upfront memsets (3 total)
    hipMemsetAsync(wsf + zstart, 0, (zend - zstart) * 4, stream);
    hipMemsetAsync(wsf + fstart, 0xFF, (fend - fstart) * 4, stream);
    hipMemsetAsync(hist, 0, (size_t)NALLBINS * 4, stream);

    // weight pre-split (independent of everything else)
    k_presplit_all<<<576, 256, 0, stream>>>(root, sess_theta, know_theta, in_proj_w,
                                            out_proj_w, attn_his_a, attn_a, wsplit);

    k_slot_assign2<<<32, 256, 0, stream>>>(sess_rel_idx, know_rel_idx, slot_s, slot_k, scnt);
    k_sdeg_match<<<(DP + 255) / 256, 256, 0, stream>>>(sess_nodes, sess_edges, slot_s,
                                                       sdeg_s, mcnt, mhe_s, msl_s, heneed, 0);
    k_sdeg_match<<<(DP + 255) / 256, 256, 0, stream>>>(know_nodes, know_edges, slot_k,
                                                       sdeg_k, mcnt + 1, mhe_k, msl_k, heneed, DHE);

    // ---------------- merged histogram + single scan + merged bucket
    k_hist_both<<<(DE + 2 * DP + 255) / 256, 256, 0, stream>>>(edge_dst, edge_type, hist,
                                                               sess_edges, know_edges);
    k_scan_pass1<<<nbA, 256, 0, stream>>>(hist, NALLBINS, bsumV);
    k_scan_pass2p<<<1, 256, 0, stream>>>(bsumV, nbA, nullptr);
    k_scan_pass3<<<nbA, 256, 0, stream>>>(hist, NALLBINS, bsumV, soff);
    k_bucket_both<<<(DE + 2 * DP + 255) / 256, 256, 0, stream>>>(
        edge_src, edge_dst, edge_type, soff, ssrc,
        sess_nodes, sess_edges, know_nodes, know_edges, pns);

    k_wcomp_split<<<(DR * DD * DD + 255) / 256, 256, 0, stream>>>(comp, bases, warena);

    // ---------------- fused root + RGCN, stacked-K v2 (one block per 64 dsts, non-atomic kg write)
    int gemmN = (DN + 63) / 64;
    k_rgcn_fk<<<gemmN, 256, 0, stream>>>(emb, wsplit + 0 * 32768, warena, rgcn_bias,
                                         soff, hist, ssrc, kg);

    // ---------------- hypergraph aggregation
    k_hyper_agg<<<(DHE2 * 64 + 255) / 256, 256, 0, stream>>>(kg, pns, soff + NRBINS,
                                                             hist + NRBINS, heneed, efeat);
    k_accmatch2<<<256, 256, 0, stream>>>(efeat, mhe_s, msl_s, mhe_k, msl_k, mcnt, sacc_s, sacc_k);

    k_gemm_ds<<<64, 256, 0, stream>>>(sacc_s, wsplit + 1 * 32768, sess_bias, sdeg_s,
                                      nullptr, nullptr, so_s, 4096);
    k_gemm_ds<<<64, 256, 0, stream>>>(sacc_k, wsplit + 2 * 32768, know_bias, sdeg_k,
                                      nullptr, nullptr, so_k, 4096);
    k_rel_gather2<<<(2 * DB * DLR * 32 + 255) / 256, 256, 0, stream>>>(
        so_s, so_k, slot_s, slot_k, sess_rel_idx, know_rel_idx, related);

    // ---------------- context + MHA (q-GEMM gathers ctx rows from kg and writes ctx)
    k_gemm_ds<<<(DB * DLC + 63) / 64, 256, 0, stream>>>(kg, wsplit + 3 * 32768,
                                                        in_proj_b, nullptr,
                                                        context_idx, ctx, qb, DB * DLC);
    k_gemm_ds<<<(DB * 128 + 63) / 64, 256, 0, stream>>>(related, wsplit + 4 * 32768,
                                                        in_proj_b + DD, nullptr,
                                                        nullptr, nullptr, kb, DB * 128);
    k_gemm_ds<<<(DB * 128 + 63) / 64, 256, 0, stream>>>(related, wsplit + 5 * 32768,
                                                        in_proj_b + 2 * DD, nullptr,
                                                        nullptr, nullptr, vb, DB * 128);
    k_mha<<<DB * DNH, 256, 0, stream>>>(qb, kb, vb, obuf);
    k_gemm_ds<<<(DB * DLC + 63) / 64, 256, 0, stream>>>(obuf, wsplit + 6 * 32768,
                                                        out_proj_b, nullptr,
                                                        nullptr, nullptr, attrel, DB * DLC);

    // ---------------- pooling (GEMM-shaped) + score
    k_tanh_dot_ds<<<(DB * DLC + 63) / 64, 256, 0, stream>>>(attrel, wsplit + 7 * 32768,
                                                            attn_his_b, e1, DB * DLC);
    k_pool_apply<32><<<DB, 128, 0, stream>>>(attrel, e1, his, nullptr);
    k_build_ucat<<<(DB * 33 * 128 + 255) / 256, 256, 0, stream>>>(ctx, his, ucat);
    k_tanh_dot_ds<<<(DB * 33 + 63) / 64, 256, 0, stream>>>(ucat, wsplit + 8 * 32768,
                                                           attn_b, e2, DB * 33);
    k_pool_apply<33><<<DB, 128, 0, stream>>>(ucat, e2, userb, usplit);
    k_score_ds<<<gemmN, 256, 0, stream>>>(kg, usplit, rec_bias, out);
}